// Round 8
// baseline (1907.344 us; speedup 1.0000x reference)
//
#include <hip/hip_runtime.h>

#define NN 50000
#define NE 800000
#define HID 128
#define NG 2500
#define NL 4
#define ME 64       // edges (or nodes) per block
#define HST 136     // LDS tile row stride (shorts): 272B -> 2-way max on b128
#define NPB 782     // node blocks: ceil(50000/64)
#define NWG (NE/ME) // 12500 edge blocks

typedef __attribute__((ext_vector_type(8))) short short8v;
typedef __attribute__((ext_vector_type(4))) float f32x4;

__device__ __forceinline__ float sigf(float x){ return 1.0f/(1.0f+__expf(-x)); }
__device__ __forceinline__ float siluf(float x){ return x/(1.0f+__expf(-x)); }
__device__ __forceinline__ short bfr(float x){           // scalar f32->bf16 (RNE)
  unsigned u = __float_as_uint(x);
  u += 0x7fffu + ((u>>16)&1u);
  return (short)(u>>16);
}
__device__ __forceinline__ unsigned cvtpk(float lo, float hi){
  unsigned r;
  asm("v_cvt_pk_bf16_f32 %0, %1, %2" : "=v"(r) : "v"(lo), "v"(hi));
  return r;
}
__device__ __forceinline__ float bf2f(short s){
  return __uint_as_float(((unsigned)(unsigned short)s)<<16);
}

// ---------------- counting sort of edges by col ----------------
__global__ void zero_hist(int* __restrict__ hist){
  int i = blockIdx.x*256 + threadIdx.x;
  if (i < NN) hist[i] = 0;
}
__global__ void hist_kernel(const int* __restrict__ eidx, int* __restrict__ hist){
  int e = blockIdx.x*256 + threadIdx.x;
  if (e < NE) atomicAdd(&hist[eidx[NE+e]], 1);
}
__global__ __launch_bounds__(1024) void scan_kernel(const int* __restrict__ hist,
                                                    int* __restrict__ cursor){
  __shared__ int part[1024];
  int t = threadIdx.x;
  const int CH = (NN + 1023)/1024;
  int base = t*CH;
  int s = 0;
  for (int j=0;j<CH;++j){ int i=base+j; if (i<NN) s += hist[i]; }
  part[t] = s; __syncthreads();
  for (int d=1; d<1024; d<<=1){
    int v = (t>=d) ? part[t-d] : 0;
    __syncthreads();
    part[t] += v;
    __syncthreads();
  }
  int ex = (t==0) ? 0 : part[t-1];
  for (int j=0;j<CH;++j){
    int i=base+j;
    if (i<NN){ cursor[i] = ex; ex += hist[i]; }
  }
}
__global__ void scatter_kernel(const int* __restrict__ eidx, int* __restrict__ cursor,
                               int* __restrict__ se){
  int e = blockIdx.x*256 + threadIdx.x;
  if (e < NE){
    int c = eidx[NE+e];
    int pos = atomicAdd(&cursor[c], 1);
    se[pos] = e;
  }
}
// one-time: materialize sorted-order edge streams
__global__ void reorder_kernel(const int* __restrict__ eidx, const int* __restrict__ se,
                               const float* __restrict__ ea, const float* __restrict__ p,
                               const int* __restrict__ inv,
                               int2* __restrict__ rcS, float4* __restrict__ eaS,
                               float* __restrict__ emS){
  int i = blockIdx.x*256 + threadIdx.x;
  if (i < NE){
    int e = se[i];
    int2 rc; rc.x = eidx[e]; rc.y = eidx[NE+e];
    rcS[i] = rc;
    eaS[i] = *reinterpret_cast<const float4*>(ea + (size_t)e*4);
    emS[i] = (p[inv[e]] >= 0.0f) ? 1.0f : 0.0f;
  }
}

// ---- weight prepack: rows [roff,roff+128) of [L][Ktot][128] -> [L][ks4][q4][o128][kk8] bf16
__global__ void prepack_kernel(const float* __restrict__ W, short* __restrict__ out,
                               int Ktot, int roff){
  int idx = blockIdx.x*256 + threadIdx.x;
  if (idx >= NL*4*4*HID*8) return;
  int kk8 = idx & 7;
  int o   = (idx>>3) & 127;
  int q   = (idx>>10) & 3;
  int ks  = (idx>>12) & 3;
  int l   = idx >> 14;
  int k = roff + ks*32 + q*8 + kk8;
  float v = (k < Ktot) ? W[((size_t)l*Ktot + k)*HID + o] : 0.0f;
  out[idx] = bfr(v);
}

__global__ void embed_kernel(const float* __restrict__ xf, const float* __restrict__ W,
                             const float* __restrict__ b, float* __restrict__ h){
  int n = blockIdx.x; int o = threadIdx.x;
  float s = b[o];
  #pragma unroll
  for (int i=0;i<11;++i) s = fmaf(xf[n*11+i], W[i*HID+o], s);
  h[(size_t)n*HID+o] = s;
}

// ---- register-resident B fragments: lane holds [ks4][ot4] short8v (64 VGPR) ----
__device__ __forceinline__ void loadB(const short* __restrict__ Wp, short8v b[4][4],
                                      int ocol, int q, int fr){
  #pragma unroll
  for (int ks=0;ks<4;++ks)
    #pragma unroll
    for (int ot=0;ot<4;++ot)
      b[ks][ot] = *reinterpret_cast<const short8v*>(
          Wp + ((size_t)((ks*4+q)*HID) + ocol + ot*16 + fr)*8);
}

// barrier-free MFMA GEMM: [64 x 128] (LDS A) @ [128 x 128] (reg B)
__device__ __forceinline__ void gemm64r(const short* As, const short8v b[4][4],
                                        f32x4 acc[2][4], int erow, int q, int fr){
  #pragma unroll
  for (int ks=0;ks<4;++ks){
    short8v a0 = *reinterpret_cast<const short8v*>(As + (erow + fr)*HST + ks*32 + q*8);
    short8v a1 = *reinterpret_cast<const short8v*>(As + (erow + 16 + fr)*HST + ks*32 + q*8);
    #pragma unroll
    for (int ot=0;ot<4;++ot){
      acc[0][ot] = __builtin_amdgcn_mfma_f32_16x16x32_bf16(a0, b[ks][ot], acc[0][ot], 0, 0, 0);
      acc[1][ot] = __builtin_amdgcn_mfma_f32_16x16x32_bf16(a1, b[ks][ot], acc[1][ot], 0, 0, 0);
    }
  }
}

// acc -> silu(scale*acc + bias) -> bf16 LDS tile; scaleS==nullptr -> scale=1
__device__ __forceinline__ void epilogue_store(const f32x4 acc[2][4],
                                               const float* __restrict__ bias,
                                               const float* __restrict__ scaleS,
                                               short* dst, int erow, int ocol, int q, int fr)
{
  #pragma unroll
  for (int et=0; et<2; ++et){
    const int e0 = erow + et*16 + q*4;
    float s0=1.f,s1=1.f,s2=1.f,s3=1.f;
    if (scaleS){ s0=scaleS[e0]; s1=scaleS[e0+1]; s2=scaleS[e0+2]; s3=scaleS[e0+3]; }
    #pragma unroll
    for (int ot=0; ot<4; ++ot){
      int o = ocol + ot*16 + fr;
      float bv = bias[o];
      unsigned p01 = cvtpk(siluf(fmaf(s0,acc[et][ot][0],bv)), siluf(fmaf(s1,acc[et][ot][1],bv)));
      unsigned p23 = cvtpk(siluf(fmaf(s2,acc[et][ot][2],bv)), siluf(fmaf(s3,acc[et][ot][3],bv)));
      dst[(e0+0)*HST + o] = (short)p01;
      dst[(e0+1)*HST + o] = (short)(p01>>16);
      dst[(e0+2)*HST + o] = (short)p23;
      dst[(e0+3)*HST + o] = (short)(p23>>16);
    }
  }
}

#define ZACC(A) {A[0][0]=z;A[0][1]=z;A[0][2]=z;A[0][3]=z;A[1][0]=z;A[1][1]=z;A[1][2]=z;A[1][3]=z;}

// ---------------- layer-0 node projections ----------------
__global__ __launch_bounds__(256) void nodeproj_kernel(
    const float* __restrict__ h,
    const short* __restrict__ Wcp, const float* __restrict__ b1,
    const short* __restrict__ Wrp,
    short* __restrict__ A, short* __restrict__ B)
{
  __shared__ __align__(16) short hT[ME*HST];
  const int t = threadIdx.x;
  const int n0 = blockIdx.x * ME;
  const int lane = t & 63, w = t >> 6;
  const int q = lane >> 4, fr = lane & 15;
  const int erow = (w & 1) * 32, ocol = (w >> 1) * 64;
  short8v bw[4][4];
  loadB(Wcp, bw, ocol, q, fr);
  {
    int nl = t >> 2, seg = t & 3;
    int n = n0 + nl; if (n >= NN) n = NN-1;
    const float4* hp = reinterpret_cast<const float4*>(h + (size_t)n*HID + seg*32);
    #pragma unroll
    for (int bq=0;bq<4;++bq){
      float4 u = hp[bq*2], v = hp[bq*2+1];
      int4 sv;
      sv.x = (int)cvtpk(u.x,u.y); sv.y = (int)cvtpk(u.z,u.w);
      sv.z = (int)cvtpk(v.x,v.y); sv.w = (int)cvtpk(v.z,v.w);
      *reinterpret_cast<int4*>(&hT[nl*HST + seg*32 + bq*8]) = sv;
    }
  }
  __syncthreads();
  f32x4 z = {0.f,0.f,0.f,0.f};
  f32x4 acc[2][4];
  ZACC(acc);
  gemm64r(hT, bw, acc, erow, q, fr);
  loadB(Wrp, bw, ocol, q, fr);
  #pragma unroll
  for (int et=0; et<2; ++et){
    int e0 = erow + et*16 + q*4;
    #pragma unroll
    for (int ot=0; ot<4; ++ot){
      int o = ocol + ot*16 + fr;
      float bv = b1[o];
      #pragma unroll
      for (int r=0;r<4;++r){
        int n = n0 + e0 + r;
        if (n < NN) A[(size_t)n*HID + o] = bfr(acc[et][ot][r] + bv);
      }
    }
  }
  f32x4 accB[2][4];
  ZACC(accB);
  gemm64r(hT, bw, accB, erow, q, fr);
  #pragma unroll
  for (int et=0; et<2; ++et){
    int e0 = erow + et*16 + q*4;
    #pragma unroll
    for (int ot=0; ot<4; ++ot){
      int o = ocol + ot*16 + fr;
      #pragma unroll
      for (int r=0;r<4;++r){
        int n = n0 + e0 + r;
        if (n < NN) B[(size_t)n*HID + o] = bfr(accB[et][ot][r]);
      }
    }
  }
}

// ---------------- edge kernel (R6 flow, barrier-free GEMMs) ----------------
__global__ __launch_bounds__(256) void edge2_kernel(
    const short* __restrict__ A, const short* __restrict__ B,
    const float* __restrict__ x,
    const int2* __restrict__ rcS, const float4* __restrict__ eaS,
    const float* __restrict__ emS,
    const float* __restrict__ wrow,   // eW1 + l*261*128 : rows 256..260 = wd, wea
    const short* __restrict__ W2p, const float* __restrict__ b2,
    const float* __restrict__ Wg, const float* __restrict__ bg,
    const short* __restrict__ C1p, const float* __restrict__ bc1,
    const float* __restrict__ Wc2, const float* __restrict__ cb2,
    float* __restrict__ magg, float* __restrict__ xout)
{
  __shared__ __align__(16) short hidS[ME*HST];   // hidden1 -> m_pre -> hidden2
  __shared__ float wdS[HID], wgS[HID], wc2S[HID];
  __shared__ float weaS[4][HID];
  __shared__ float maskS[ME], scaleS[ME], cwS[ME], distS[ME], cdS[ME][3];
  __shared__ int colS[ME];

  const int t = threadIdx.x;
  // bijective XCD swizzle (m204)
  const int xcd = blockIdx.x & 7, sub = blockIdx.x >> 3;
  const int qq = NWG >> 3, rr = NWG & 7;
  const int bid = (xcd < rr ? xcd*(qq+1) : rr*(qq+1) + (xcd-rr)*qq) + sub;
  const int i0 = bid * ME;

  const int lane = t & 63, w = t >> 6;
  const int q = lane >> 4, fr = lane & 15;
  const int erow = (w & 1) * 32, ocol = (w >> 1) * 64;

  short8v bw[4][4];
  loadB(W2p, bw, ocol, q, fr);

  // per-thread gathers (4 threads/edge, 32 channels each)
  const int el = t >> 2, seg = t & 3;
  const int2 rc = rcS[i0 + el];
  const int4* Ap = reinterpret_cast<const int4*>(A + (size_t)rc.y*HID + seg*32);
  const int4* Bp = reinterpret_cast<const int4*>(B + (size_t)rc.x*HID + seg*32);
  int4 av0=Ap[0], av1=Ap[1], av2=Ap[2], av3=Ap[3];
  int4 bv0=Bp[0], bv1=Bp[1], bv2=Bp[2], bv3=Bp[3];
  float4 eav = eaS[i0 + el];

  if (t < HID){
    wdS[t] = wrow[256*HID + t];
    wgS[t] = Wg[t]; wc2S[t] = Wc2[t];
    #pragma unroll
    for (int j=0;j<4;++j) weaS[j][t] = wrow[(257+j)*HID + t];
  }
  if (t < ME){
    int2 rc2 = rcS[i0 + t];
    colS[t] = rc2.y; maskS[t] = emS[i0 + t];
    float dx = x[rc2.y*3+0]-x[rc2.x*3+0];
    float dy = x[rc2.y*3+1]-x[rc2.x*3+1];
    float dz = x[rc2.y*3+2]-x[rc2.x*3+2];
    cdS[t][0]=dx; cdS[t][1]=dy; cdS[t][2]=dz;
    distS[t] = sqrtf(dx*dx+dy*dy+dz*dz);
  }
  __syncthreads();                              // (1) setup arrays

  // hidden1 = silu(A[col] + B[row] + dist*wd + ea@wea)
  {
    float de = distS[el];
    const int4 avs[4] = {av0,av1,av2,av3};
    const int4 bvs[4] = {bv0,bv1,bv2,bv3};
    #pragma unroll
    for (int bq=0;bq<4;++bq){
      short8v a8 = *reinterpret_cast<const short8v*>(&avs[bq]);
      short8v b8 = *reinterpret_cast<const short8v*>(&bvs[bq]);
      float f[8];
      #pragma unroll
      for (int j=0;j<8;++j){
        int o = seg*32 + bq*8 + j;
        float v = bf2f(a8[j]) + bf2f(b8[j]) + de*wdS[o]
                + eav.x*weaS[0][o] + eav.y*weaS[1][o]
                + eav.z*weaS[2][o] + eav.w*weaS[3][o];
        f[j] = siluf(v);
      }
      int4 sv;
      sv.x = (int)cvtpk(f[0],f[1]); sv.y = (int)cvtpk(f[2],f[3]);
      sv.z = (int)cvtpk(f[4],f[5]); sv.w = (int)cvtpk(f[6],f[7]);
      *reinterpret_cast<int4*>(&hidS[el*HST + seg*32 + bq*8]) = sv;
    }
  }
  __syncthreads();                              // (2) publish hidden1

  f32x4 z = {0.f,0.f,0.f,0.f};
  f32x4 acc2[2][4];
  ZACC(acc2);
  gemm64r(hidS, bw, acc2, erow, q, fr);         // m_pre accum
  loadB(C1p, bw, ocol, q, fr);                  // prefetch Wc1 frags (hidden under epilogue+gate)
  __syncthreads();                              // (3) hidden1 reads done
  epilogue_store(acc2, b2, nullptr, hidS, erow, ocol, q, fr);   // m_pre in-place
  __syncthreads();                              // (4) publish m_pre

  // gate = sigmoid(m_pre . Wg + bg) * mask   (4 threads per edge)
  {
    int eg = t >> 2, g = t & 3;
    float p = 0.f;
    #pragma unroll
    for (int bq=0;bq<4;++bq){
      short8v s = *reinterpret_cast<const short8v*>(&hidS[eg*HST + g*32 + bq*8]);
      #pragma unroll
      for (int j=0;j<8;++j) p += bf2f(s[j]) * wgS[g*32 + bq*8 + j];
    }
    p += __shfl_xor(p, 1); p += __shfl_xor(p, 2);
    if (g == 0) scaleS[eg] = sigf(p + bg[0]) * maskS[eg];
  }
  __syncthreads();                              // (5) publish scaleS

  // magg[col] += m_pre * scale (segmented; atomics issue early, hide under gemm3)
  {
    int o = t & 127, half = t >> 7;
    int ib = half*32;
    float accv = 0.f;
    int curc = colS[ib];
    #pragma unroll 4
    for (int j=0;j<32;++j){
      int i = ib + j;
      int cc = colS[i];
      if (cc != curc){
        atomicAdd(&magg[(size_t)curc*HID + o], accv);
        accv = 0.f; curc = cc;
      }
      accv += bf2f(hidS[i*HST + o]) * scaleS[i];
    }
    atomicAdd(&magg[(size_t)curc*HID + o], accv);
  }

  // hidden2 = silu(scale * (m_pre @ Wc1) + bc1)
  f32x4 acc3[2][4];
  ZACC(acc3);
  gemm64r(hidS, bw, acc3, erow, q, fr);
  __syncthreads();                              // (6) m_pre reads done
  epilogue_store(acc3, bc1, scaleS, hidS, erow, ocol, q, fr);   // hidden2 in-place
  __syncthreads();                              // (7) publish hidden2

  // cw = hidden2 . Wc2 + cb2
  {
    int eg = t >> 2, g = t & 3;
    float p = 0.f;
    #pragma unroll
    for (int bq=0;bq<4;++bq){
      short8v s = *reinterpret_cast<const short8v*>(&hidS[eg*HST + g*32 + bq*8]);
      #pragma unroll
      for (int j=0;j<8;++j) p += bf2f(s[j]) * wc2S[g*32 + bq*8 + j];
    }
    p += __shfl_xor(p, 1); p += __shfl_xor(p, 2);
    if (g == 0) cwS[eg] = p + cb2[0];
  }
  __syncthreads();                              // (8) publish cwS

  // x_out[col] += coord_diff * cw (segmented)
  if (t < 6){
    int d = t % 3, half = t / 3;
    int ib = half*32;
    float accx = 0.f;
    int curc = colS[ib];
    for (int j=0;j<32;++j){
      int i = ib + j;
      int cc = colS[i];
      if (cc != curc){
        atomicAdd(&xout[curc*3+d], accx);
        accx = 0.f; curc = cc;
      }
      accx += cdS[i][d] * cwS[i];
    }
    atomicAdd(&xout[curc*3+d], accx);
  }
}

// ---- fused node MLP + next-layer projections (barrier-free GEMMs) ----
__global__ __launch_bounds__(256) void node2f_kernel(
    float* __restrict__ h, const float* __restrict__ magg,
    const short* __restrict__ W1ap, const short* __restrict__ W1bp,
    const float* __restrict__ bn1,
    const short* __restrict__ Wn2p, const float* __restrict__ bn2,
    const short* __restrict__ Wcp, const float* __restrict__ b1n,
    const short* __restrict__ Wrp,
    short* __restrict__ A, short* __restrict__ B, int doProj)
{
  __shared__ __align__(16) short hT[ME*HST];
  __shared__ __align__(16) short mT[ME*HST];
  const int t = threadIdx.x;
  const int n0 = blockIdx.x * ME;
  const int lane = t & 63, w = t >> 6;
  const int q = lane >> 4, fr = lane & 15;
  const int erow = (w & 1) * 32, ocol = (w >> 1) * 64;
  short8v bw[4][4];
  loadB(W1ap, bw, ocol, q, fr);
  {
    int nl = t >> 2, seg = t & 3;
    int n = n0 + nl; if (n >= NN) n = NN-1;
    const float4* hp = reinterpret_cast<const float4*>(h + (size_t)n*HID + seg*32);
    const float4* mp = reinterpret_cast<const float4*>(magg + (size_t)n*HID + seg*32);
    #pragma unroll
    for (int bq=0;bq<4;++bq){
      float4 u = hp[bq*2], v = hp[bq*2+1];
      int4 sv;
      sv.x = (int)cvtpk(u.x,u.y); sv.y = (int)cvtpk(u.z,u.w);
      sv.z = (int)cvtpk(v.x,v.y); sv.w = (int)cvtpk(v.z,v.w);
      *reinterpret_cast<int4*>(&hT[nl*HST + seg*32 + bq*8]) = sv;
      float4 u2 = mp[bq*2], v2 = mp[bq*2+1];
      int4 sv2;
      sv2.x = (int)cvtpk(u2.x,u2.y); sv2.y = (int)cvtpk(u2.z,u2.w);
      sv2.z = (int)cvtpk(v2.x,v2.y); sv2.w = (int)cvtpk(v2.z,v2.w);
      *reinterpret_cast<int4*>(&mT[nl*HST + seg*32 + bq*8]) = sv2;
    }
  }
  __syncthreads();                              // publish hT, mT
  f32x4 z = {0.f,0.f,0.f,0.f};
  f32x4 acc[2][4];
  ZACC(acc);
  gemm64r(hT, bw, acc, erow, q, fr);
  loadB(W1bp, bw, ocol, q, fr);
  gemm64r(mT, bw, acc, erow, q, fr);            // accumulates
  loadB(Wn2p, bw, ocol, q, fr);
  __syncthreads();                              // mT reads done
  epilogue_store(acc, bn1, nullptr, mT, erow, ocol, q, fr);   // silu1 -> mT
  __syncthreads();                              // publish mT

  f32x4 acc2[2][4];
  ZACC(acc2);
  gemm64r(mT, bw, acc2, erow, q, fr);
  if (doProj) loadB(Wcp, bw, ocol, q, fr);

  // h_new -> global h, bf16(h_new) -> hT (hT reads ended before "publish mT" barrier)
  #pragma unroll
  for (int et=0; et<2; ++et){
    int e0 = erow + et*16 + q*4;
    #pragma unroll
    for (int ot=0; ot<4; ++ot){
      int o = ocol + ot*16 + fr;
      float bv = bn2[o];
      float hn[4];
      #pragma unroll
      for (int r=0;r<4;++r){
        int n = n0 + e0 + r;
        float hv = 0.f;
        if (n < NN){
          size_t idx = (size_t)n*HID + o;
          hv = h[idx] + acc2[et][ot][r] + bv;
          h[idx] = hv;
        }
        hn[r] = hv;
      }
      if (doProj){
        unsigned p01 = cvtpk(hn[0],hn[1]), p23 = cvtpk(hn[2],hn[3]);
        hT[(e0+0)*HST + o] = (short)p01;
        hT[(e0+1)*HST + o] = (short)(p01>>16);
        hT[(e0+2)*HST + o] = (short)p23;
        hT[(e0+3)*HST + o] = (short)(p23>>16);
      }
    }
  }
  if (!doProj) return;
  __syncthreads();                              // publish hT (h_new)

  f32x4 accA[2][4];
  ZACC(accA);
  gemm64r(hT, bw, accA, erow, q, fr);
  loadB(Wrp, bw, ocol, q, fr);
  #pragma unroll
  for (int et=0; et<2; ++et){
    int e0 = erow + et*16 + q*4;
    #pragma unroll
    for (int ot=0; ot<4; ++ot){
      int o = ocol + ot*16 + fr;
      float bv = b1n[o];
      #pragma unroll
      for (int r=0;r<4;++r){
        int n = n0 + e0 + r;
        if (n < NN) A[(size_t)n*HID + o] = bfr(accA[et][ot][r] + bv);
      }
    }
  }
  f32x4 accB[2][4];
  ZACC(accB);
  gemm64r(hT, bw, accB, erow, q, fr);
  #pragma unroll
  for (int et=0; et<2; ++et){
    int e0 = erow + et*16 + q*4;
    #pragma unroll
    for (int ot=0; ot<4; ++ot){
      int o = ocol + ot*16 + fr;
      #pragma unroll
      for (int r=0;r<4;++r){
        int n = n0 + e0 + r;
        if (n < NN) B[(size_t)n*HID + o] = bfr(accB[et][ot][r]);
      }
    }
  }
}

__global__ void pool_kernel(const float* __restrict__ h, const int* __restrict__ batch,
                            float* __restrict__ sums, float* __restrict__ counts){
  int o  = threadIdx.x;
  int n0 = blockIdx.x * 16;
  int curg = batch[n0];
  float accv = 0.f, cnt = 0.f;
  for (int j=0;j<16;++j){
    int n = n0 + j;
    int g = batch[n];
    if (g != curg){
      atomicAdd(&sums[(size_t)curg*HID+o], accv);
      if (o==0) atomicAdd(&counts[curg], cnt);
      accv = 0.f; cnt = 0.f; curg = g;
    }
    accv += h[(size_t)n*HID+o];
    cnt  += 1.f;
  }
  atomicAdd(&sums[(size_t)curg*HID+o], accv);
  if (o==0) atomicAdd(&counts[curg], cnt);
}

__global__ void out_kernel(const float* __restrict__ sums, const float* __restrict__ counts,
                           const float* __restrict__ rW, const float* __restrict__ rb,
                           float* __restrict__ out){
  int g = blockIdx.x; int t = threadIdx.x;
  float v = sums[(size_t)g*HID + t]*rW[t] + sums[(size_t)g*HID + 64 + t]*rW[64+t];
  #pragma unroll
  for (int off=32; off>0; off>>=1) v += __shfl_down(v, off);
  if (t==0) out[g] = v / fmaxf(counts[g], 1.0f) + rb[0];
}

extern "C" void kernel_launch(void* const* d_in, const int* in_sizes, int n_in,
                              void* d_out, int out_size, void* d_ws, size_t ws_size,
                              hipStream_t stream)
{
  const float* x_feat = (const float*)d_in[0];
  const float* pos    = (const float*)d_in[1];
  const float* eattr  = (const float*)d_in[2];
  const float* p      = (const float*)d_in[3];
  const float* embW   = (const float*)d_in[4];
  const float* embB   = (const float*)d_in[5];
  const float* eW1    = (const float*)d_in[6];
  const float* eb1    = (const float*)d_in[7];
  const float* eW2    = (const float*)d_in[8];
  const float* eb2    = (const float*)d_in[9];
  const float* gW     = (const float*)d_in[10];
  const float* gb     = (const float*)d_in[11];
  const float* nW1    = (const float*)d_in[12];
  const float* nb1    = (const float*)d_in[13];
  const float* nW2    = (const float*)d_in[14];
  const float* nb2    = (const float*)d_in[15];
  const float* cW1    = (const float*)d_in[16];
  const float* cb1    = (const float*)d_in[17];
  const float* cW2    = (const float*)d_in[18];
  const float* cb2    = (const float*)d_in[19];
  const float* rW     = (const float*)d_in[20];
  const float* rb     = (const float*)d_in[21];
  const int* eidx     = (const int*)d_in[22];
  const int* einv     = (const int*)d_in[23];
  const int* batch    = (const int*)d_in[24];

  float* ws = (float*)d_ws;
  float* h      = ws;  ws += (size_t)NN*HID;
  float* magg   = ws;  ws += (size_t)NN*HID;
  float* xA     = ws;  ws += NN*3;
  float* xB     = ws;  ws += NN*3;
  float* sums   = ws;  ws += (size_t)NG*HID;
  float* counts = ws;  ws += NG;
  int*   hist   = (int*)ws;  ws += NN;
  int*   se     = (int*)ws;  ws += NE;
  int2*  rcS    = (int2*)ws;  ws += (size_t)NE*2;
  float4* eaS   = (float4*)ws; ws += (size_t)NE*4;
  float* emS    = ws;  ws += NE;
  short* Abuf = (short*)ws;  ws += (size_t)NN*HID/2;
  short* Bbuf = (short*)ws;  ws += (size_t)NN*HID/2;
  const size_t PK = (size_t)NL*4*4*HID*8;   // shorts per packed array
  short* W1cp  = (short*)ws;
  short* W1rp  = W1cp  + PK;
  short* W2p   = W1rp  + PK;
  short* C1p   = W2p   + PK;
  short* Wn1ap = C1p   + PK;
  short* Wn1bp = Wn1ap + PK;
  short* Wn2p  = Wn1bp + PK;

  // counting sort of edges by col, then materialize sorted streams
  zero_hist<<<(NN+255)/256, 256, 0, stream>>>(hist);
  hist_kernel<<<(NE+255)/256, 256, 0, stream>>>(eidx, hist);
  scan_kernel<<<1, 1024, 0, stream>>>(hist, hist);
  scatter_kernel<<<(NE+255)/256, 256, 0, stream>>>(eidx, hist, se);
  reorder_kernel<<<(NE+255)/256, 256, 0, stream>>>(eidx, se, eattr, p, einv,
                                                   rcS, eaS, emS);

  // prepack bf16 weights (each [L][4][4][128][8])
  const int PG = (int)((PK + 255)/256);
  prepack_kernel<<<PG, 256, 0, stream>>>(eW1, W1cp, 261, 0);
  prepack_kernel<<<PG, 256, 0, stream>>>(eW1, W1rp, 261, 128);
  prepack_kernel<<<PG, 256, 0, stream>>>(eW2, W2p, 128, 0);
  prepack_kernel<<<PG, 256, 0, stream>>>(cW1, C1p, 128, 0);
  prepack_kernel<<<PG, 256, 0, stream>>>(nW1, Wn1ap, 256, 0);
  prepack_kernel<<<PG, 256, 0, stream>>>(nW1, Wn1bp, 256, 128);
  prepack_kernel<<<PG, 256, 0, stream>>>(nW2, Wn2p, 128, 0);

  hipMemcpyAsync(xA, pos, sizeof(float)*NN*3, hipMemcpyDeviceToDevice, stream);
  embed_kernel<<<NN, HID, 0, stream>>>(x_feat, embW, embB, h);
  nodeproj_kernel<<<NPB, 256, 0, stream>>>(h, W1cp, eb1, W1rp, Abuf, Bbuf);

  float* xc = xA; float* xn = xB;
  for (int l=0;l<NL;++l){
    const size_t wofs = (size_t)l*4*4096;
    const size_t wofsn = (size_t)(l+1)*4*4096;
    hipMemsetAsync(magg, 0, sizeof(float)*(size_t)NN*HID, stream);
    hipMemcpyAsync(xn, xc, sizeof(float)*NN*3, hipMemcpyDeviceToDevice, stream);
    edge2_kernel<<<NWG, 256, 0, stream>>>(Abuf, Bbuf, xc, rcS, eaS, emS,
        eW1 + (size_t)l*261*HID,
        W2p + wofs, eb2 + l*HID,
        gW  + l*HID, gb + l,
        C1p + wofs, cb1 + l*HID,
        cW2 + l*HID, cb2 + l,
        magg, xn);
    int doProj = (l+1 < NL);
    node2f_kernel<<<NPB, 256, 0, stream>>>(h, magg,
        Wn1ap + wofs, Wn1bp + wofs, nb1 + l*HID,
        Wn2p + wofs, nb2 + l*HID,
        W1cp + (doProj?wofsn:0), eb1 + (doProj?(l+1)*HID:0),
        W1rp + (doProj?wofsn:0),
        Abuf, Bbuf, doProj);
    float* tmp = xc; xc = xn; xn = tmp;
  }
  hipMemsetAsync(sums, 0, sizeof(float)*((size_t)NG*HID + NG), stream);
  pool_kernel<<<NN/16, HID, 0, stream>>>(h, batch, sums, counts);
  out_kernel<<<NG, 64, 0, stream>>>(sums, counts, rW, rb, (float*)d_out);
}

// Round 9
// 1848.708 us; speedup vs baseline: 1.0317x; 1.0317x over previous
//
#include <hip/hip_runtime.h>

#define NN 50000
#define NE 800000
#define HID 128
#define NG 2500
#define NL 4
#define ME 64       // edges (or nodes) per block
#define HST 136     // LDS tile row stride (shorts): 272B -> 2-way max on b128
#define NPB 782     // node blocks: ceil(50000/64)
#define NWG (NE/ME) // 12500 edge blocks

typedef __attribute__((ext_vector_type(8))) short short8v;
typedef __attribute__((ext_vector_type(4))) float f32x4;

__device__ __forceinline__ float sigf(float x){ return 1.0f/(1.0f+__expf(-x)); }
__device__ __forceinline__ float siluf(float x){ return x/(1.0f+__expf(-x)); }
__device__ __forceinline__ short bfr(float x){           // scalar f32->bf16 (RNE)
  unsigned u = __float_as_uint(x);
  u += 0x7fffu + ((u>>16)&1u);
  return (short)(u>>16);
}
__device__ __forceinline__ unsigned cvtpk(float lo, float hi){
  unsigned r;
  asm("v_cvt_pk_bf16_f32 %0, %1, %2" : "=v"(r) : "v"(lo), "v"(hi));
  return r;
}
__device__ __forceinline__ float bf2f(short s){
  return __uint_as_float(((unsigned)(unsigned short)s)<<16);
}

// ---------------- counting sort of edges by col ----------------
__global__ void zero_hist(int* __restrict__ hist){
  int i = blockIdx.x*256 + threadIdx.x;
  if (i < NN) hist[i] = 0;
}
__global__ void hist_kernel(const int* __restrict__ eidx, int* __restrict__ hist){
  int e = blockIdx.x*256 + threadIdx.x;
  if (e < NE) atomicAdd(&hist[eidx[NE+e]], 1);
}
__global__ __launch_bounds__(1024) void scan_kernel(const int* __restrict__ hist,
                                                    int* __restrict__ cursor){
  __shared__ int part[1024];
  int t = threadIdx.x;
  const int CH = (NN + 1023)/1024;
  int base = t*CH;
  int s = 0;
  for (int j=0;j<CH;++j){ int i=base+j; if (i<NN) s += hist[i]; }
  part[t] = s; __syncthreads();
  for (int d=1; d<1024; d<<=1){
    int v = (t>=d) ? part[t-d] : 0;
    __syncthreads();
    part[t] += v;
    __syncthreads();
  }
  int ex = (t==0) ? 0 : part[t-1];
  for (int j=0;j<CH;++j){
    int i=base+j;
    if (i<NN){ cursor[i] = ex; ex += hist[i]; }
  }
}
__global__ void scatter_kernel(const int* __restrict__ eidx, int* __restrict__ cursor,
                               int* __restrict__ se){
  int e = blockIdx.x*256 + threadIdx.x;
  if (e < NE){
    int c = eidx[NE+e];
    int pos = atomicAdd(&cursor[c], 1);
    se[pos] = e;
  }
}
// one-time: materialize sorted-order edge streams
__global__ void reorder_kernel(const int* __restrict__ eidx, const int* __restrict__ se,
                               const float* __restrict__ ea, const float* __restrict__ p,
                               const int* __restrict__ inv,
                               int2* __restrict__ rcS, float4* __restrict__ eaS,
                               float* __restrict__ emS){
  int i = blockIdx.x*256 + threadIdx.x;
  if (i < NE){
    int e = se[i];
    int2 rc; rc.x = eidx[e]; rc.y = eidx[NE+e];
    rcS[i] = rc;
    eaS[i] = *reinterpret_cast<const float4*>(ea + (size_t)e*4);
    emS[i] = (p[inv[e]] >= 0.0f) ? 1.0f : 0.0f;
  }
}

// ---- weight prepack: rows [roff,roff+128) of [L][Ktot][128] -> [L][ks4][q4][o128][kk8] bf16
__global__ void prepack_kernel(const float* __restrict__ W, short* __restrict__ out,
                               int Ktot, int roff){
  int idx = blockIdx.x*256 + threadIdx.x;
  if (idx >= NL*4*4*HID*8) return;
  int kk8 = idx & 7;
  int o   = (idx>>3) & 127;
  int q   = (idx>>10) & 3;
  int ks  = (idx>>12) & 3;
  int l   = idx >> 14;
  int k = roff + ks*32 + q*8 + kk8;
  float v = (k < Ktot) ? W[((size_t)l*Ktot + k)*HID + o] : 0.0f;
  out[idx] = bfr(v);
}
// ---- tiny vector prepack: [L][128] f32 -> bf16
__global__ void prepack_vec_kernel(const float* __restrict__ W, short* __restrict__ out){
  int idx = blockIdx.x*256 + threadIdx.x;
  if (idx < NL*HID) out[idx] = bfr(W[idx]);
}

__global__ void embed_kernel(const float* __restrict__ xf, const float* __restrict__ W,
                             const float* __restrict__ b, float* __restrict__ h){
  int n = blockIdx.x; int o = threadIdx.x;
  float s = b[o];
  #pragma unroll
  for (int i=0;i<11;++i) s = fmaf(xf[n*11+i], W[i*HID+o], s);
  h[(size_t)n*HID+o] = s;
}

// ---------------- MFMA tile-GEMM: [64 x 128] (LDS bf16) @ [128 x 128] (prepacked) ----
__device__ __forceinline__ void gemm64(const short* As, int astride,
                                       const short* Wp, int nks,
                                       short* bkS, f32x4 acc[2][4], int t)
{
  const int lane = t & 63, w = t >> 6;
  const int q = lane >> 4, fr = lane & 15;
  const int erow = (w & 1) * 32;
  const int ocol = (w >> 1) * 64;
  const int4* g = reinterpret_cast<const int4*>(Wp);
  int4* bkw = reinterpret_cast<int4*>(bkS);
  int4 p0 = g[t], p1 = g[256 + t];
  for (int ks = 0; ks < nks; ++ks){
    const int buf = (ks & 1) * 512;            // int4 units (4096 shorts)
    bkw[buf + t] = p0; bkw[buf + 256 + t] = p1;
    __syncthreads();
    if (ks + 1 < nks){ p0 = g[(ks+1)*512 + t]; p1 = g[(ks+1)*512 + 256 + t]; }
    const short* bb = bkS + buf*8 + q*1024;
    short8v a[2], b[4];
    #pragma unroll
    for (int et=0; et<2; ++et)
      a[et] = *reinterpret_cast<const short8v*>(As + (erow + et*16 + fr)*astride + ks*32 + q*8);
    #pragma unroll
    for (int ot=0; ot<4; ++ot)
      b[ot] = *reinterpret_cast<const short8v*>(bb + (ocol + ot*16 + fr)*8);
    #pragma unroll
    for (int et=0; et<2; ++et)
      #pragma unroll
      for (int ot=0; ot<4; ++ot)
        acc[et][ot] = __builtin_amdgcn_mfma_f32_16x16x32_bf16(a[et], b[ot], acc[et][ot], 0, 0, 0);
  }
  __syncthreads();
}

// acc -> silu(scale*acc + bias) -> bf16 LDS tile [64][HST]; scaleS==nullptr -> scale=1
__device__ __forceinline__ void epilogue_store(const f32x4 acc[2][4],
                                               const float* __restrict__ bias,
                                               const float* __restrict__ scaleS,
                                               short* dst, int t)
{
  const int lane = t & 63, w = t >> 6;
  const int q = lane >> 4, fr = lane & 15;
  #pragma unroll
  for (int et=0; et<2; ++et){
    const int e0 = (w&1)*32 + et*16 + q*4;
    float s0=1.f,s1=1.f,s2=1.f,s3=1.f;
    if (scaleS){ s0=scaleS[e0]; s1=scaleS[e0+1]; s2=scaleS[e0+2]; s3=scaleS[e0+3]; }
    #pragma unroll
    for (int ot=0; ot<4; ++ot){
      int o = (w>>1)*64 + ot*16 + fr;
      float bv = bias[o];
      unsigned p01 = cvtpk(siluf(fmaf(s0,acc[et][ot][0],bv)), siluf(fmaf(s1,acc[et][ot][1],bv)));
      unsigned p23 = cvtpk(siluf(fmaf(s2,acc[et][ot][2],bv)), siluf(fmaf(s3,acc[et][ot][3],bv)));
      dst[(e0+0)*HST + o] = (short)p01;
      dst[(e0+1)*HST + o] = (short)(p01>>16);
      dst[(e0+2)*HST + o] = (short)p23;
      dst[(e0+3)*HST + o] = (short)(p23>>16);
    }
  }
}

// ---------------- layer-0 node projections: A = bf16(h@W1hc + b1), B = bf16(h@W1hr) ----
__global__ __launch_bounds__(256) void nodeproj_kernel(
    const float* __restrict__ h,
    const short* __restrict__ Wcp, const float* __restrict__ b1,
    const short* __restrict__ Wrp,
    short* __restrict__ A, short* __restrict__ B)
{
  __shared__ __align__(16) short hT[ME*HST];
  __shared__ __align__(16) short bkS[2*4096];
  const int t = threadIdx.x;
  const int n0 = blockIdx.x * ME;
  {
    int nl = t >> 2, seg = t & 3;
    int n = n0 + nl; if (n >= NN) n = NN-1;
    const float4* hp = reinterpret_cast<const float4*>(h + (size_t)n*HID + seg*32);
    #pragma unroll
    for (int bq=0;bq<4;++bq){
      float4 u = hp[bq*2], v = hp[bq*2+1];
      int4 sv;
      sv.x = (int)cvtpk(u.x,u.y); sv.y = (int)cvtpk(u.z,u.w);
      sv.z = (int)cvtpk(v.x,v.y); sv.w = (int)cvtpk(v.z,v.w);
      *reinterpret_cast<int4*>(&hT[nl*HST + seg*32 + bq*8]) = sv;
    }
  }
  f32x4 z = {0.f,0.f,0.f,0.f};
  f32x4 accA[2][4], accB[2][4];
  #pragma unroll
  for (int i=0;i<2;++i){ accA[i][0]=z;accA[i][1]=z;accA[i][2]=z;accA[i][3]=z;
                         accB[i][0]=z;accB[i][1]=z;accB[i][2]=z;accB[i][3]=z; }
  gemm64(hT, HST, Wcp, 4, bkS, accA, t);
  gemm64(hT, HST, Wrp, 4, bkS, accB, t);
  const int lane = t & 63, w = t >> 6;
  const int q = lane >> 4, fr = lane & 15;
  #pragma unroll
  for (int et=0; et<2; ++et){
    int e0 = (w&1)*32 + et*16 + q*4;
    #pragma unroll
    for (int ot=0; ot<4; ++ot){
      int o = (w>>1)*64 + ot*16 + fr;
      float bv = b1[o];
      #pragma unroll
      for (int r=0;r<4;++r){
        int n = n0 + e0 + r;
        if (n < NN){
          A[(size_t)n*HID + o] = bfr(accA[et][ot][r] + bv);
          B[(size_t)n*HID + o] = bfr(accB[et][ot][r]);
        }
      }
    }
  }
}

// ---------------- edge kernel (R6 structure; gate & cw via padded-B MFMA) ----------------
__global__ __launch_bounds__(256) void edge2_kernel(
    const short* __restrict__ A, const short* __restrict__ B,
    const float* __restrict__ x,
    const int2* __restrict__ rcS, const float4* __restrict__ eaS,
    const float* __restrict__ emS,
    const float* __restrict__ wrow,   // eW1 + l*261*128 : rows 256..260 = wd, wea
    const short* __restrict__ W2p, const float* __restrict__ b2,
    const short* __restrict__ Wgp, const float* __restrict__ bg,
    const short* __restrict__ C1p, const float* __restrict__ bc1,
    const short* __restrict__ Wc2p, const float* __restrict__ cb2,
    float* __restrict__ magg, float* __restrict__ xout)
{
  __shared__ __align__(16) short hidS[ME*HST];   // hidden1 -> m_pre -> hidden2
  __shared__ __align__(16) short bkS[2*4096];
  __shared__ float wdS[HID];
  __shared__ float weaS[4][HID];
  __shared__ float maskS[ME], scaleS[ME], cwS[ME], distS[ME], cdS[ME][3];
  __shared__ int colS[ME];

  const int t = threadIdx.x;
  // bijective XCD swizzle (m204)
  const int xcd = blockIdx.x & 7, sub = blockIdx.x >> 3;
  const int qq = NWG >> 3, rr = NWG & 7;
  const int bid = (xcd < rr ? xcd*(qq+1) : rr*(qq+1) + (xcd-rr)*qq) + sub;
  const int i0 = bid * ME;

  const int lane = t & 63, w = t >> 6;
  const int q = lane >> 4, fr = lane & 15;
  const int erow = (w & 1) * 32;

  // padded-B fragments for gate (Wg) and cw (Wc2): only B-row 0 (fr==0) nonzero
  short8v bgf[4], wcf[4];
  {
    short8v zs = {0,0,0,0,0,0,0,0};
    #pragma unroll
    for (int ks=0;ks<4;++ks){ bgf[ks]=zs; wcf[ks]=zs; }
    if (fr == 0 && w < 2){
      #pragma unroll
      for (int ks=0;ks<4;++ks){
        bgf[ks] = *reinterpret_cast<const short8v*>(Wgp  + ks*32 + q*8);
        wcf[ks] = *reinterpret_cast<const short8v*>(Wc2p + ks*32 + q*8);
      }
    }
  }

  // per-thread gathers (4 threads/edge, 32 channels each)
  const int el = t >> 2, seg = t & 3;
  const int2 rc = rcS[i0 + el];
  const int4* Ap = reinterpret_cast<const int4*>(A + (size_t)rc.y*HID + seg*32);
  const int4* Bp = reinterpret_cast<const int4*>(B + (size_t)rc.x*HID + seg*32);
  int4 av0=Ap[0], av1=Ap[1], av2=Ap[2], av3=Ap[3];
  int4 bv0=Bp[0], bv1=Bp[1], bv2=Bp[2], bv3=Bp[3];
  float4 eav = eaS[i0 + el];

  if (t < HID){
    wdS[t] = wrow[256*HID + t];
    #pragma unroll
    for (int j=0;j<4;++j) weaS[j][t] = wrow[(257+j)*HID + t];
  }
  if (t < ME){
    int2 rc2 = rcS[i0 + t];
    colS[t] = rc2.y; maskS[t] = emS[i0 + t];
    float dx = x[rc2.y*3+0]-x[rc2.x*3+0];
    float dy = x[rc2.y*3+1]-x[rc2.x*3+1];
    float dz = x[rc2.y*3+2]-x[rc2.x*3+2];
    cdS[t][0]=dx; cdS[t][1]=dy; cdS[t][2]=dz;
    distS[t] = sqrtf(dx*dx+dy*dy+dz*dz);
  }
  __syncthreads();

  // hidden1 = silu(A[col] + B[row] + dist*wd + ea@wea)
  {
    float de = distS[el];
    const int4 avs[4] = {av0,av1,av2,av3};
    const int4 bvs[4] = {bv0,bv1,bv2,bv3};
    #pragma unroll
    for (int bq=0;bq<4;++bq){
      short8v a8 = *reinterpret_cast<const short8v*>(&avs[bq]);
      short8v b8 = *reinterpret_cast<const short8v*>(&bvs[bq]);
      float f[8];
      #pragma unroll
      for (int j=0;j<8;++j){
        int o = seg*32 + bq*8 + j;
        float v = bf2f(a8[j]) + bf2f(b8[j]) + de*wdS[o]
                + eav.x*weaS[0][o] + eav.y*weaS[1][o]
                + eav.z*weaS[2][o] + eav.w*weaS[3][o];
        f[j] = siluf(v);
      }
      int4 sv;
      sv.x = (int)cvtpk(f[0],f[1]); sv.y = (int)cvtpk(f[2],f[3]);
      sv.z = (int)cvtpk(f[4],f[5]); sv.w = (int)cvtpk(f[6],f[7]);
      *reinterpret_cast<int4*>(&hidS[el*HST + seg*32 + bq*8]) = sv;
    }
  }
  // gemm64's first loop-top barrier publishes hidS

  f32x4 z = {0.f,0.f,0.f,0.f};
  f32x4 acc2[2][4];
  #pragma unroll
  for (int i=0;i<2;++i){ acc2[i][0]=z; acc2[i][1]=z; acc2[i][2]=z; acc2[i][3]=z; }
  gemm64(hidS, HST, W2p, 4, bkS, acc2, t);
  epilogue_store(acc2, b2, nullptr, hidS, t);     // m_pre (in-place)
  __syncthreads();                                // publish m_pre

  // gate = sigmoid(m_pre . Wg + bg) * mask — padded-B MFMA on waves 0,1
  if (w < 2){
    f32x4 accg0 = z, accg1 = z;
    #pragma unroll
    for (int ks=0;ks<4;++ks){
      short8v a0 = *reinterpret_cast<const short8v*>(&hidS[(erow + fr)*HST + ks*32 + q*8]);
      short8v a1 = *reinterpret_cast<const short8v*>(&hidS[(erow + 16 + fr)*HST + ks*32 + q*8]);
      accg0 = __builtin_amdgcn_mfma_f32_16x16x32_bf16(a0, bgf[ks], accg0, 0, 0, 0);
      accg1 = __builtin_amdgcn_mfma_f32_16x16x32_bf16(a1, bgf[ks], accg1, 0, 0, 0);
    }
    if (fr == 0){
      float bgv = bg[0];
      #pragma unroll
      for (int r=0;r<4;++r){
        int e0 = erow + q*4 + r, e1 = erow + 16 + q*4 + r;
        scaleS[e0] = sigf(accg0[r] + bgv) * maskS[e0];
        scaleS[e1] = sigf(accg1[r] + bgv) * maskS[e1];
      }
    }
  }
  __syncthreads();                                // publish scaleS

  // magg[col] += m_pre * scale (segmented; cols sorted)
  {
    int o = t & 127, half = t >> 7;
    int ib = half*32;
    float accv = 0.f;
    int curc = colS[ib];
    #pragma unroll 4
    for (int j=0;j<32;++j){
      int i = ib + j;
      int cc = colS[i];
      if (cc != curc){
        atomicAdd(&magg[(size_t)curc*HID + o], accv);
        accv = 0.f; curc = cc;
      }
      accv += bf2f(hidS[i*HST + o]) * scaleS[i];
    }
    atomicAdd(&magg[(size_t)curc*HID + o], accv);
  }
  __syncthreads();

  // hidden2 = silu(scale * (m_pre @ Wc1) + bc1)
  f32x4 acc3[2][4];
  #pragma unroll
  for (int i=0;i<2;++i){ acc3[i][0]=z; acc3[i][1]=z; acc3[i][2]=z; acc3[i][3]=z; }
  gemm64(hidS, HST, C1p, 4, bkS, acc3, t);
  epilogue_store(acc3, bc1, scaleS, hidS, t);     // hidden2 (in-place)
  __syncthreads();                                // publish hidden2

  // cw = hidden2 . Wc2 + cb2 — padded-B MFMA on waves 0,1
  if (w < 2){
    f32x4 accw0 = z, accw1 = z;
    #pragma unroll
    for (int ks=0;ks<4;++ks){
      short8v a0 = *reinterpret_cast<const short8v*>(&hidS[(erow + fr)*HST + ks*32 + q*8]);
      short8v a1 = *reinterpret_cast<const short8v*>(&hidS[(erow + 16 + fr)*HST + ks*32 + q*8]);
      accw0 = __builtin_amdgcn_mfma_f32_16x16x32_bf16(a0, wcf[ks], accw0, 0, 0, 0);
      accw1 = __builtin_amdgcn_mfma_f32_16x16x32_bf16(a1, wcf[ks], accw1, 0, 0, 0);
    }
    if (fr == 0){
      float cbv = cb2[0];
      #pragma unroll
      for (int r=0;r<4;++r){
        cwS[erow + q*4 + r]      = accw0[r] + cbv;
        cwS[erow + 16 + q*4 + r] = accw1[r] + cbv;
      }
    }
  }
  __syncthreads();                                // publish cwS

  // x_out[col] += coord_diff * cw (segmented)
  if (t < 6){
    int d = t % 3, half = t / 3;
    int ib = half*32;
    float accx = 0.f;
    int curc = colS[ib];
    for (int j=0;j<32;++j){
      int i = ib + j;
      int cc = colS[i];
      if (cc != curc){
        atomicAdd(&xout[curc*3+d], accx);
        accx = 0.f; curc = cc;
      }
      accx += cdS[i][d] * cwS[i];
    }
    atomicAdd(&xout[curc*3+d], accx);
  }
}

// ---- fused node MLP + next-layer projections (R6 version) ----
__global__ __launch_bounds__(256) void node2f_kernel(
    float* __restrict__ h, const float* __restrict__ magg,
    const short* __restrict__ W1ap, const short* __restrict__ W1bp,
    const float* __restrict__ bn1,
    const short* __restrict__ Wn2p, const float* __restrict__ bn2,
    const short* __restrict__ Wcp, const float* __restrict__ b1n,
    const short* __restrict__ Wrp,
    short* __restrict__ A, short* __restrict__ B, int doProj)
{
  __shared__ __align__(16) short hT[ME*HST];
  __shared__ __align__(16) short mT[ME*HST];
  __shared__ __align__(16) short bkS[2*4096];
  const int t = threadIdx.x;
  const int n0 = blockIdx.x * ME;
  {
    int nl = t >> 2, seg = t & 3;
    int n = n0 + nl; if (n >= NN) n = NN-1;
    const float4* hp = reinterpret_cast<const float4*>(h + (size_t)n*HID + seg*32);
    const float4* mp = reinterpret_cast<const float4*>(magg + (size_t)n*HID + seg*32);
    #pragma unroll
    for (int bq=0;bq<4;++bq){
      float4 u = hp[bq*2], v = hp[bq*2+1];
      int4 sv;
      sv.x = (int)cvtpk(u.x,u.y); sv.y = (int)cvtpk(u.z,u.w);
      sv.z = (int)cvtpk(v.x,v.y); sv.w = (int)cvtpk(v.z,v.w);
      *reinterpret_cast<int4*>(&hT[nl*HST + seg*32 + bq*8]) = sv;
      float4 u2 = mp[bq*2], v2 = mp[bq*2+1];
      int4 sv2;
      sv2.x = (int)cvtpk(u2.x,u2.y); sv2.y = (int)cvtpk(u2.z,u2.w);
      sv2.z = (int)cvtpk(v2.x,v2.y); sv2.w = (int)cvtpk(v2.z,v2.w);
      *reinterpret_cast<int4*>(&mT[nl*HST + seg*32 + bq*8]) = sv2;
    }
  }
  f32x4 z = {0.f,0.f,0.f,0.f};
  f32x4 acc[2][4];
  #pragma unroll
  for (int i=0;i<2;++i){ acc[i][0]=z; acc[i][1]=z; acc[i][2]=z; acc[i][3]=z; }
  gemm64(hT, HST, W1ap, 4, bkS, acc, t);
  gemm64(mT, HST, W1bp, 4, bkS, acc, t);        // accumulates
  epilogue_store(acc, bn1, nullptr, mT, t);      // silu1 -> mT
  __syncthreads();

  f32x4 acc2[2][4];
  #pragma unroll
  for (int i=0;i<2;++i){ acc2[i][0]=z; acc2[i][1]=z; acc2[i][2]=z; acc2[i][3]=z; }
  gemm64(mT, HST, Wn2p, 4, bkS, acc2, t);

  const int lane = t & 63, w = t >> 6;
  const int q = lane >> 4, fr = lane & 15;
  #pragma unroll
  for (int et=0; et<2; ++et){
    int e0 = (w&1)*32 + et*16 + q*4;
    #pragma unroll
    for (int ot=0; ot<4; ++ot){
      int o = (w>>1)*64 + ot*16 + fr;
      float bv = bn2[o];
      float hn[4];
      #pragma unroll
      for (int r=0;r<4;++r){
        int n = n0 + e0 + r;
        float hv = 0.f;
        if (n < NN){
          size_t idx = (size_t)n*HID + o;
          hv = h[idx] + acc2[et][ot][r] + bv;
          h[idx] = hv;
        }
        hn[r] = hv;
      }
      if (doProj){
        unsigned p01 = cvtpk(hn[0],hn[1]), p23 = cvtpk(hn[2],hn[3]);
        hT[(e0+0)*HST + o] = (short)p01;
        hT[(e0+1)*HST + o] = (short)(p01>>16);
        hT[(e0+2)*HST + o] = (short)p23;
        hT[(e0+3)*HST + o] = (short)(p23>>16);
      }
    }
  }
  if (!doProj) return;
  // (gemm64's loop-top barrier publishes hT)

  f32x4 accA[2][4], accB[2][4];
  #pragma unroll
  for (int i=0;i<2;++i){ accA[i][0]=z;accA[i][1]=z;accA[i][2]=z;accA[i][3]=z;
                         accB[i][0]=z;accB[i][1]=z;accB[i][2]=z;accB[i][3]=z; }
  gemm64(hT, HST, Wcp, 4, bkS, accA, t);
  gemm64(hT, HST, Wrp, 4, bkS, accB, t);
  #pragma unroll
  for (int et=0; et<2; ++et){
    int e0 = (w&1)*32 + et*16 + q*4;
    #pragma unroll
    for (int ot=0; ot<4; ++ot){
      int o = (w>>1)*64 + ot*16 + fr;
      float bv = b1n[o];
      #pragma unroll
      for (int r=0;r<4;++r){
        int n = n0 + e0 + r;
        if (n < NN){
          A[(size_t)n*HID + o] = bfr(accA[et][ot][r] + bv);
          B[(size_t)n*HID + o] = bfr(accB[et][ot][r]);
        }
      }
    }
  }
}

__global__ void pool_kernel(const float* __restrict__ h, const int* __restrict__ batch,
                            float* __restrict__ sums, float* __restrict__ counts){
  int o  = threadIdx.x;
  int n0 = blockIdx.x * 16;
  int curg = batch[n0];
  float accv = 0.f, cnt = 0.f;
  for (int j=0;j<16;++j){
    int n = n0 + j;
    int g = batch[n];
    if (g != curg){
      atomicAdd(&sums[(size_t)curg*HID+o], accv);
      if (o==0) atomicAdd(&counts[curg], cnt);
      accv = 0.f; cnt = 0.f; curg = g;
    }
    accv += h[(size_t)n*HID+o];
    cnt  += 1.f;
  }
  atomicAdd(&sums[(size_t)curg*HID+o], accv);
  if (o==0) atomicAdd(&counts[curg], cnt);
}

__global__ void out_kernel(const float* __restrict__ sums, const float* __restrict__ counts,
                           const float* __restrict__ rW, const float* __restrict__ rb,
                           float* __restrict__ out){
  int g = blockIdx.x; int t = threadIdx.x;
  float v = sums[(size_t)g*HID + t]*rW[t] + sums[(size_t)g*HID + 64 + t]*rW[64+t];
  #pragma unroll
  for (int off=32; off>0; off>>=1) v += __shfl_down(v, off);
  if (t==0) out[g] = v / fmaxf(counts[g], 1.0f) + rb[0];
}

extern "C" void kernel_launch(void* const* d_in, const int* in_sizes, int n_in,
                              void* d_out, int out_size, void* d_ws, size_t ws_size,
                              hipStream_t stream)
{
  const float* x_feat = (const float*)d_in[0];
  const float* pos    = (const float*)d_in[1];
  const float* eattr  = (const float*)d_in[2];
  const float* p      = (const float*)d_in[3];
  const float* embW   = (const float*)d_in[4];
  const float* embB   = (const float*)d_in[5];
  const float* eW1    = (const float*)d_in[6];
  const float* eb1    = (const float*)d_in[7];
  const float* eW2    = (const float*)d_in[8];
  const float* eb2    = (const float*)d_in[9];
  const float* gW     = (const float*)d_in[10];
  const float* gb     = (const float*)d_in[11];
  const float* nW1    = (const float*)d_in[12];
  const float* nb1    = (const float*)d_in[13];
  const float* nW2    = (const float*)d_in[14];
  const float* nb2    = (const float*)d_in[15];
  const float* cW1    = (const float*)d_in[16];
  const float* cb1    = (const float*)d_in[17];
  const float* cW2    = (const float*)d_in[18];
  const float* cb2    = (const float*)d_in[19];
  const float* rW     = (const float*)d_in[20];
  const float* rb     = (const float*)d_in[21];
  const int* eidx     = (const int*)d_in[22];
  const int* einv     = (const int*)d_in[23];
  const int* batch    = (const int*)d_in[24];

  float* ws = (float*)d_ws;
  float* h      = ws;  ws += (size_t)NN*HID;
  float* magg   = ws;  ws += (size_t)NN*HID;
  float* xA     = ws;  ws += NN*3;
  float* xB     = ws;  ws += NN*3;
  float* sums   = ws;  ws += (size_t)NG*HID;
  float* counts = ws;  ws += NG;
  int*   hist   = (int*)ws;  ws += NN;
  int*   se     = (int*)ws;  ws += NE;
  int2*  rcS    = (int2*)ws;  ws += (size_t)NE*2;
  float4* eaS   = (float4*)ws; ws += (size_t)NE*4;
  float* emS    = ws;  ws += NE;
  short* Abuf = (short*)ws;  ws += (size_t)NN*HID/2;
  short* Bbuf = (short*)ws;  ws += (size_t)NN*HID/2;
  const size_t PK = (size_t)NL*4*4*HID*8;   // shorts per packed array
  short* W1cp  = (short*)ws;
  short* W1rp  = W1cp  + PK;
  short* W2p   = W1rp  + PK;
  short* C1p   = W2p   + PK;
  short* Wn1ap = C1p   + PK;
  short* Wn1bp = Wn1ap + PK;
  short* Wn2p  = Wn1bp + PK;
  short* Wgp   = Wn2p  + PK;               // [L][128] bf16
  short* Wc2p  = Wgp   + (size_t)NL*HID;

  // counting sort of edges by col, then materialize sorted streams
  zero_hist<<<(NN+255)/256, 256, 0, stream>>>(hist);
  hist_kernel<<<(NE+255)/256, 256, 0, stream>>>(eidx, hist);
  scan_kernel<<<1, 1024, 0, stream>>>(hist, hist);
  scatter_kernel<<<(NE+255)/256, 256, 0, stream>>>(eidx, hist, se);
  reorder_kernel<<<(NE+255)/256, 256, 0, stream>>>(eidx, se, eattr, p, einv,
                                                   rcS, eaS, emS);

  // prepack bf16 weights
  const int PG = (int)((PK + 255)/256);
  prepack_kernel<<<PG, 256, 0, stream>>>(eW1, W1cp, 261, 0);
  prepack_kernel<<<PG, 256, 0, stream>>>(eW1, W1rp, 261, 128);
  prepack_kernel<<<PG, 256, 0, stream>>>(eW2, W2p, 128, 0);
  prepack_kernel<<<PG, 256, 0, stream>>>(cW1, C1p, 128, 0);
  prepack_kernel<<<PG, 256, 0, stream>>>(nW1, Wn1ap, 256, 0);
  prepack_kernel<<<PG, 256, 0, stream>>>(nW1, Wn1bp, 256, 128);
  prepack_kernel<<<PG, 256, 0, stream>>>(nW2, Wn2p, 128, 0);
  prepack_vec_kernel<<<(NL*HID+255)/256, 256, 0, stream>>>(gW, Wgp);
  prepack_vec_kernel<<<(NL*HID+255)/256, 256, 0, stream>>>(cW2, Wc2p);

  hipMemcpyAsync(xA, pos, sizeof(float)*NN*3, hipMemcpyDeviceToDevice, stream);
  embed_kernel<<<NN, HID, 0, stream>>>(x_feat, embW, embB, h);
  nodeproj_kernel<<<NPB, 256, 0, stream>>>(h, W1cp, eb1, W1rp, Abuf, Bbuf);

  float* xc = xA; float* xn = xB;
  for (int l=0;l<NL;++l){
    const size_t wofs = (size_t)l*4*4096;
    const size_t wofsn = (size_t)(l+1)*4*4096;
    hipMemsetAsync(magg, 0, sizeof(float)*(size_t)NN*HID, stream);
    hipMemcpyAsync(xn, xc, sizeof(float)*NN*3, hipMemcpyDeviceToDevice, stream);
    edge2_kernel<<<NWG, 256, 0, stream>>>(Abuf, Bbuf, xc, rcS, eaS, emS,
        eW1 + (size_t)l*261*HID,
        W2p + wofs, eb2 + l*HID,
        Wgp + l*HID, gb + l,
        C1p + wofs, cb1 + l*HID,
        Wc2p + l*HID, cb2 + l,
        magg, xn);
    int doProj = (l+1 < NL);
    node2f_kernel<<<NPB, 256, 0, stream>>>(h, magg,
        Wn1ap + wofs, Wn1bp + wofs, nb1 + l*HID,
        Wn2p + wofs, nb2 + l*HID,
        W1cp + (doProj?wofsn:0), eb1 + (doProj?(l+1)*HID:0),
        W1rp + (doProj?wofsn:0),
        Abuf, Bbuf, doProj);
    float* tmp = xc; xc = xn; xn = tmp;
  }
  hipMemsetAsync(sums, 0, sizeof(float)*((size_t)NG*HID + NG), stream);
  pool_kernel<<<NN/16, HID, 0, stream>>>(h, batch, sums, counts);
  out_kernel<<<NG, 64, 0, stream>>>(sums, counts, rW, rb, (float*)d_out);
}

// Round 10
// 1675.052 us; speedup vs baseline: 1.1387x; 1.1037x over previous
//
#include <hip/hip_runtime.h>

#define NN 50000
#define NE 800000
#define HID 128
#define NG 2500
#define NL 4
#define ME 64        // node-tile rows
#define MEE 128      // edges per edge-block (512 threads)
#define HST 136      // LDS tile row stride (shorts): 272B -> 2-way max on b128
#define NPB 782      // node blocks: ceil(50000/64)
#define NWGE (NE/MEE) // 6250 edge blocks

typedef __attribute__((ext_vector_type(8))) short short8v;
typedef __attribute__((ext_vector_type(4))) float f32x4;

__device__ __forceinline__ float sigf(float x){ return 1.0f/(1.0f+__expf(-x)); }
__device__ __forceinline__ float siluf(float x){ return x/(1.0f+__expf(-x)); }
__device__ __forceinline__ short bfr(float x){           // scalar f32->bf16 (RNE)
  unsigned u = __float_as_uint(x);
  u += 0x7fffu + ((u>>16)&1u);
  return (short)(u>>16);
}
__device__ __forceinline__ unsigned cvtpk(float lo, float hi){
  unsigned r;
  asm("v_cvt_pk_bf16_f32 %0, %1, %2" : "=v"(r) : "v"(lo), "v"(hi));
  return r;
}
__device__ __forceinline__ float bf2f(short s){
  return __uint_as_float(((unsigned)(unsigned short)s)<<16);
}

// ---------------- counting sort of edges by col ----------------
__global__ void zero_hist(int* __restrict__ hist){
  int i = blockIdx.x*256 + threadIdx.x;
  if (i < NN) hist[i] = 0;
}
__global__ void hist_kernel(const int* __restrict__ eidx, int* __restrict__ hist){
  int e = blockIdx.x*256 + threadIdx.x;
  if (e < NE) atomicAdd(&hist[eidx[NE+e]], 1);
}
__global__ __launch_bounds__(1024) void scan_kernel(const int* __restrict__ hist,
                                                    int* __restrict__ cursor){
  __shared__ int part[1024];
  int t = threadIdx.x;
  const int CH = (NN + 1023)/1024;
  int base = t*CH;
  int s = 0;
  for (int j=0;j<CH;++j){ int i=base+j; if (i<NN) s += hist[i]; }
  part[t] = s; __syncthreads();
  for (int d=1; d<1024; d<<=1){
    int v = (t>=d) ? part[t-d] : 0;
    __syncthreads();
    part[t] += v;
    __syncthreads();
  }
  int ex = (t==0) ? 0 : part[t-1];
  for (int j=0;j<CH;++j){
    int i=base+j;
    if (i<NN){ cursor[i] = ex; ex += hist[i]; }
  }
}
__global__ void scatter_kernel(const int* __restrict__ eidx, int* __restrict__ cursor,
                               int* __restrict__ se){
  int e = blockIdx.x*256 + threadIdx.x;
  if (e < NE){
    int c = eidx[NE+e];
    int pos = atomicAdd(&cursor[c], 1);
    se[pos] = e;
  }
}
// one-time: materialize sorted-order edge streams
__global__ void reorder_kernel(const int* __restrict__ eidx, const int* __restrict__ se,
                               const float* __restrict__ ea, const float* __restrict__ p,
                               const int* __restrict__ inv,
                               int2* __restrict__ rcS, float4* __restrict__ eaS,
                               float* __restrict__ emS){
  int i = blockIdx.x*256 + threadIdx.x;
  if (i < NE){
    int e = se[i];
    int2 rc; rc.x = eidx[e]; rc.y = eidx[NE+e];
    rcS[i] = rc;
    eaS[i] = *reinterpret_cast<const float4*>(ea + (size_t)e*4);
    emS[i] = (p[inv[e]] >= 0.0f) ? 1.0f : 0.0f;
  }
}

// ---- weight prepack: rows [roff,roff+128) of [L][Ktot][128] -> [L][ks4][q4][o128][kk8] bf16
__global__ void prepack_kernel(const float* __restrict__ W, short* __restrict__ out,
                               int Ktot, int roff){
  int idx = blockIdx.x*256 + threadIdx.x;
  if (idx >= NL*4*4*HID*8) return;
  int kk8 = idx & 7;
  int o   = (idx>>3) & 127;
  int q   = (idx>>10) & 3;
  int ks  = (idx>>12) & 3;
  int l   = idx >> 14;
  int k = roff + ks*32 + q*8 + kk8;
  float v = (k < Ktot) ? W[((size_t)l*Ktot + k)*HID + o] : 0.0f;
  out[idx] = bfr(v);
}

__global__ void embed_kernel(const float* __restrict__ xf, const float* __restrict__ W,
                             const float* __restrict__ b, float* __restrict__ h){
  int n = blockIdx.x; int o = threadIdx.x;
  float s = b[o];
  #pragma unroll
  for (int i=0;i<11;++i) s = fmaf(xf[n*11+i], W[i*HID+o], s);
  h[(size_t)n*HID+o] = s;
}

// ---------------- MFMA tile-GEMM (256 threads): [64 x 128] @ [128 x 128] ----
__device__ __forceinline__ void gemm64(const short* As, int astride,
                                       const short* Wp, int nks,
                                       short* bkS, f32x4 acc[2][4], int t)
{
  const int lane = t & 63, w = t >> 6;
  const int q = lane >> 4, fr = lane & 15;
  const int erow = (w & 1) * 32;
  const int ocol = (w >> 1) * 64;
  const int4* g = reinterpret_cast<const int4*>(Wp);
  int4* bkw = reinterpret_cast<int4*>(bkS);
  int4 p0 = g[t], p1 = g[256 + t];
  for (int ks = 0; ks < nks; ++ks){
    const int buf = (ks & 1) * 512;            // int4 units (4096 shorts)
    bkw[buf + t] = p0; bkw[buf + 256 + t] = p1;
    __syncthreads();
    if (ks + 1 < nks){ p0 = g[(ks+1)*512 + t]; p1 = g[(ks+1)*512 + 256 + t]; }
    const short* bb = bkS + buf*8 + q*1024;
    short8v a[2], b[4];
    #pragma unroll
    for (int et=0; et<2; ++et)
      a[et] = *reinterpret_cast<const short8v*>(As + (erow + et*16 + fr)*astride + ks*32 + q*8);
    #pragma unroll
    for (int ot=0; ot<4; ++ot)
      b[ot] = *reinterpret_cast<const short8v*>(bb + (ocol + ot*16 + fr)*8);
    #pragma unroll
    for (int et=0; et<2; ++et)
      #pragma unroll
      for (int ot=0; ot<4; ++ot)
        acc[et][ot] = __builtin_amdgcn_mfma_f32_16x16x32_bf16(a[et], b[ot], acc[et][ot], 0, 0, 0);
  }
  __syncthreads();
}

// ---------------- MFMA tile-GEMM (512 threads): [128 x 128] @ [128 x 128] ----
// wave w in [0,8): erow=(w&3)*32, ocol=(w>>2)*64; one int4 stage-store per thread
__device__ __forceinline__ void gemm128(const short* As,
                                        const short* Wp,
                                        short* bkS, f32x4 acc[2][4], int t)
{
  const int lane = t & 63, w = t >> 6;
  const int q = lane >> 4, fr = lane & 15;
  const int erow = (w & 3) * 32;
  const int ocol = (w >> 2) * 64;
  const int4* g = reinterpret_cast<const int4*>(Wp);
  int4* bkw = reinterpret_cast<int4*>(bkS);
  int4 p0 = g[t];
  for (int ks = 0; ks < 4; ++ks){
    const int buf = (ks & 1) * 512;
    bkw[buf + t] = p0;
    __syncthreads();
    if (ks + 1 < 4) p0 = g[(ks+1)*512 + t];
    const short* bb = bkS + buf*8 + q*1024;
    short8v a[2], b[4];
    #pragma unroll
    for (int et=0; et<2; ++et)
      a[et] = *reinterpret_cast<const short8v*>(As + (erow + et*16 + fr)*HST + ks*32 + q*8);
    #pragma unroll
    for (int ot=0; ot<4; ++ot)
      b[ot] = *reinterpret_cast<const short8v*>(bb + (ocol + ot*16 + fr)*8);
    #pragma unroll
    for (int et=0; et<2; ++et)
      #pragma unroll
      for (int ot=0; ot<4; ++ot)
        acc[et][ot] = __builtin_amdgcn_mfma_f32_16x16x32_bf16(a[et], b[ot], acc[et][ot], 0, 0, 0);
  }
  __syncthreads();
}

// acc -> silu(scale*acc + bias) -> bf16 LDS tile (256-thread tiling)
__device__ __forceinline__ void epilogue_store(const f32x4 acc[2][4],
                                               const float* __restrict__ bias,
                                               const float* __restrict__ scaleS,
                                               short* dst, int t)
{
  const int lane = t & 63, w = t >> 6;
  const int q = lane >> 4, fr = lane & 15;
  #pragma unroll
  for (int et=0; et<2; ++et){
    const int e0 = (w&1)*32 + et*16 + q*4;
    float s0=1.f,s1=1.f,s2=1.f,s3=1.f;
    if (scaleS){ s0=scaleS[e0]; s1=scaleS[e0+1]; s2=scaleS[e0+2]; s3=scaleS[e0+3]; }
    #pragma unroll
    for (int ot=0; ot<4; ++ot){
      int o = (w>>1)*64 + ot*16 + fr;
      float bv = bias[o];
      unsigned p01 = cvtpk(siluf(fmaf(s0,acc[et][ot][0],bv)), siluf(fmaf(s1,acc[et][ot][1],bv)));
      unsigned p23 = cvtpk(siluf(fmaf(s2,acc[et][ot][2],bv)), siluf(fmaf(s3,acc[et][ot][3],bv)));
      dst[(e0+0)*HST + o] = (short)p01;
      dst[(e0+1)*HST + o] = (short)(p01>>16);
      dst[(e0+2)*HST + o] = (short)p23;
      dst[(e0+3)*HST + o] = (short)(p23>>16);
    }
  }
}

// acc -> silu(scale*acc + bias) -> bf16 LDS tile (512-thread tiling)
__device__ __forceinline__ void epilogue_store128(const f32x4 acc[2][4],
                                                  const float* __restrict__ bias,
                                                  const float* __restrict__ scaleS,
                                                  short* dst, int t)
{
  const int lane = t & 63, w = t >> 6;
  const int q = lane >> 4, fr = lane & 15;
  #pragma unroll
  for (int et=0; et<2; ++et){
    const int e0 = (w&3)*32 + et*16 + q*4;
    float s0=1.f,s1=1.f,s2=1.f,s3=1.f;
    if (scaleS){ s0=scaleS[e0]; s1=scaleS[e0+1]; s2=scaleS[e0+2]; s3=scaleS[e0+3]; }
    #pragma unroll
    for (int ot=0; ot<4; ++ot){
      int o = (w>>2)*64 + ot*16 + fr;
      float bv = bias[o];
      unsigned p01 = cvtpk(siluf(fmaf(s0,acc[et][ot][0],bv)), siluf(fmaf(s1,acc[et][ot][1],bv)));
      unsigned p23 = cvtpk(siluf(fmaf(s2,acc[et][ot][2],bv)), siluf(fmaf(s3,acc[et][ot][3],bv)));
      dst[(e0+0)*HST + o] = (short)p01;
      dst[(e0+1)*HST + o] = (short)(p01>>16);
      dst[(e0+2)*HST + o] = (short)p23;
      dst[(e0+3)*HST + o] = (short)(p23>>16);
    }
  }
}

// ---------------- layer-0 node projections ----------------
__global__ __launch_bounds__(256) void nodeproj_kernel(
    const float* __restrict__ h,
    const short* __restrict__ Wcp, const float* __restrict__ b1,
    const short* __restrict__ Wrp,
    short* __restrict__ A, short* __restrict__ B)
{
  __shared__ __align__(16) short hT[ME*HST];
  __shared__ __align__(16) short bkS[2*4096];
  const int t = threadIdx.x;
  const int n0 = blockIdx.x * ME;
  {
    int nl = t >> 2, seg = t & 3;
    int n = n0 + nl; if (n >= NN) n = NN-1;
    const float4* hp = reinterpret_cast<const float4*>(h + (size_t)n*HID + seg*32);
    #pragma unroll
    for (int bq=0;bq<4;++bq){
      float4 u = hp[bq*2], v = hp[bq*2+1];
      int4 sv;
      sv.x = (int)cvtpk(u.x,u.y); sv.y = (int)cvtpk(u.z,u.w);
      sv.z = (int)cvtpk(v.x,v.y); sv.w = (int)cvtpk(v.z,v.w);
      *reinterpret_cast<int4*>(&hT[nl*HST + seg*32 + bq*8]) = sv;
    }
  }
  f32x4 z = {0.f,0.f,0.f,0.f};
  f32x4 accA[2][4], accB[2][4];
  #pragma unroll
  for (int i=0;i<2;++i){ accA[i][0]=z;accA[i][1]=z;accA[i][2]=z;accA[i][3]=z;
                         accB[i][0]=z;accB[i][1]=z;accB[i][2]=z;accB[i][3]=z; }
  gemm64(hT, HST, Wcp, 4, bkS, accA, t);
  gemm64(hT, HST, Wrp, 4, bkS, accB, t);
  const int lane = t & 63, w = t >> 6;
  const int q = lane >> 4, fr = lane & 15;
  #pragma unroll
  for (int et=0; et<2; ++et){
    int e0 = (w&1)*32 + et*16 + q*4;
    #pragma unroll
    for (int ot=0; ot<4; ++ot){
      int o = (w>>1)*64 + ot*16 + fr;
      float bv = b1[o];
      #pragma unroll
      for (int r=0;r<4;++r){
        int n = n0 + e0 + r;
        if (n < NN){
          A[(size_t)n*HID + o] = bfr(accA[et][ot][r] + bv);
          B[(size_t)n*HID + o] = bfr(accB[et][ot][r]);
        }
      }
    }
  }
}

// ---------------- edge kernel: R6 flow, 128 edges / 512 threads ----------------
__global__ __launch_bounds__(512, 4) void edge2_kernel(
    const short* __restrict__ A, const short* __restrict__ B,
    const float* __restrict__ x,
    const int2* __restrict__ rcS, const float4* __restrict__ eaS,
    const float* __restrict__ emS,
    const float* __restrict__ wrow,   // eW1 + l*261*128 : rows 256..260 = wd, wea
    const short* __restrict__ W2p, const float* __restrict__ b2,
    const float* __restrict__ Wg, const float* __restrict__ bg,
    const short* __restrict__ C1p, const float* __restrict__ bc1,
    const float* __restrict__ Wc2, const float* __restrict__ cb2,
    float* __restrict__ magg, float* __restrict__ xout)
{
  __shared__ __align__(16) short hidS[MEE*HST];  // hidden1 -> m_pre -> hidden2
  __shared__ __align__(16) short bkS[2*4096];
  __shared__ float wdS[HID], wgS[HID], wc2S[HID];
  __shared__ float weaS[4][HID];
  __shared__ float maskS[MEE], scaleS[MEE], cwS[MEE], distS[MEE], cdS[MEE][3];
  __shared__ int colS[MEE];

  const int t = threadIdx.x;
  // bijective XCD swizzle (m204)
  const int xcd = blockIdx.x & 7, sub = blockIdx.x >> 3;
  const int qq = NWGE >> 3, rr = NWGE & 7;
  const int bid = (xcd < rr ? xcd*(qq+1) : rr*(qq+1) + (xcd-rr)*qq) + sub;
  const int i0 = bid * MEE;

  // per-thread gathers (4 threads/edge, 32 channels each)
  const int el = t >> 2, seg = t & 3;
  const int2 rc = rcS[i0 + el];
  const int4* Ap = reinterpret_cast<const int4*>(A + (size_t)rc.y*HID + seg*32);
  const int4* Bp = reinterpret_cast<const int4*>(B + (size_t)rc.x*HID + seg*32);
  int4 av0=Ap[0], av1=Ap[1], av2=Ap[2], av3=Ap[3];
  int4 bv0=Bp[0], bv1=Bp[1], bv2=Bp[2], bv3=Bp[3];
  float4 eav = eaS[i0 + el];

  if (t < HID){
    wdS[t] = wrow[256*HID + t];
    wgS[t] = Wg[t]; wc2S[t] = Wc2[t];
    #pragma unroll
    for (int j=0;j<4;++j) weaS[j][t] = wrow[(257+j)*HID + t];
  }
  if (t < MEE){
    int2 rc2 = rcS[i0 + t];
    colS[t] = rc2.y; maskS[t] = emS[i0 + t];
    float dx = x[rc2.y*3+0]-x[rc2.x*3+0];
    float dy = x[rc2.y*3+1]-x[rc2.x*3+1];
    float dz = x[rc2.y*3+2]-x[rc2.x*3+2];
    cdS[t][0]=dx; cdS[t][1]=dy; cdS[t][2]=dz;
    distS[t] = sqrtf(dx*dx+dy*dy+dz*dz);
  }
  __syncthreads();

  // hidden1 = silu(A[col] + B[row] + dist*wd + ea@wea)
  {
    float de = distS[el];
    const int4 avs[4] = {av0,av1,av2,av3};
    const int4 bvs[4] = {bv0,bv1,bv2,bv3};
    #pragma unroll
    for (int bq=0;bq<4;++bq){
      short8v a8 = *reinterpret_cast<const short8v*>(&avs[bq]);
      short8v b8 = *reinterpret_cast<const short8v*>(&bvs[bq]);
      float f[8];
      #pragma unroll
      for (int j=0;j<8;++j){
        int o = seg*32 + bq*8 + j;
        float v = bf2f(a8[j]) + bf2f(b8[j]) + de*wdS[o]
                + eav.x*weaS[0][o] + eav.y*weaS[1][o]
                + eav.z*weaS[2][o] + eav.w*weaS[3][o];
        f[j] = siluf(v);
      }
      int4 sv;
      sv.x = (int)cvtpk(f[0],f[1]); sv.y = (int)cvtpk(f[2],f[3]);
      sv.z = (int)cvtpk(f[4],f[5]); sv.w = (int)cvtpk(f[6],f[7]);
      *reinterpret_cast<int4*>(&hidS[el*HST + seg*32 + bq*8]) = sv;
    }
  }
  // gemm128's first loop-top barrier publishes hidS

  f32x4 z = {0.f,0.f,0.f,0.f};
  f32x4 acc2[2][4];
  #pragma unroll
  for (int i=0;i<2;++i){ acc2[i][0]=z; acc2[i][1]=z; acc2[i][2]=z; acc2[i][3]=z; }
  gemm128(hidS, W2p, bkS, acc2, t);
  epilogue_store128(acc2, b2, nullptr, hidS, t);  // m_pre (in-place)
  __syncthreads();                                // publish m_pre

  // gate = sigmoid(m_pre . Wg + bg) * mask   (4 threads/edge)
  {
    int eg = t >> 2, g = t & 3;
    float p = 0.f;
    #pragma unroll
    for (int bq=0;bq<4;++bq){
      short8v s = *reinterpret_cast<const short8v*>(&hidS[eg*HST + g*32 + bq*8]);
      #pragma unroll
      for (int j=0;j<8;++j) p += bf2f(s[j]) * wgS[g*32 + bq*8 + j];
    }
    p += __shfl_xor(p, 1); p += __shfl_xor(p, 2);
    if (g == 0) scaleS[eg] = sigf(p + bg[0]) * maskS[eg];
  }
  __syncthreads();                                // publish scaleS

  // magg[col] += m_pre * scale (segmented; cols sorted; 4 halves x 32 edges)
  {
    int o = t & 127, half = t >> 7;
    int ib = half*32;
    float accv = 0.f;
    int curc = colS[ib];
    #pragma unroll 4
    for (int j=0;j<32;++j){
      int i = ib + j;
      int cc = colS[i];
      if (cc != curc){
        atomicAdd(&magg[(size_t)curc*HID + o], accv);
        accv = 0.f; curc = cc;
      }
      accv += bf2f(hidS[i*HST + o]) * scaleS[i];
    }
    atomicAdd(&magg[(size_t)curc*HID + o], accv);
  }
  __syncthreads();

  // hidden2 = silu(scale * (m_pre @ Wc1) + bc1)
  f32x4 acc3[2][4];
  #pragma unroll
  for (int i=0;i<2;++i){ acc3[i][0]=z; acc3[i][1]=z; acc3[i][2]=z; acc3[i][3]=z; }
  gemm128(hidS, C1p, bkS, acc3, t);
  epilogue_store128(acc3, bc1, scaleS, hidS, t);  // hidden2 (in-place)
  __syncthreads();                                // publish hidden2

  // cw = hidden2 . Wc2 + cb2
  {
    int eg = t >> 2, g = t & 3;
    float p = 0.f;
    #pragma unroll
    for (int bq=0;bq<4;++bq){
      short8v s = *reinterpret_cast<const short8v*>(&hidS[eg*HST + g*32 + bq*8]);
      #pragma unroll
      for (int j=0;j<8;++j) p += bf2f(s[j]) * wc2S[g*32 + bq*8 + j];
    }
    p += __shfl_xor(p, 1); p += __shfl_xor(p, 2);
    if (g == 0) cwS[eg] = p + cb2[0];
  }
  __syncthreads();                                // publish cwS

  // x_out[col] += coord_diff * cw (segmented; 4 halves x 3 dims)
  if (t < 12){
    int d = t % 3, half = t / 3;
    int ib = half*32;
    float accx = 0.f;
    int curc = colS[ib];
    for (int j=0;j<32;++j){
      int i = ib + j;
      int cc = colS[i];
      if (cc != curc){
        atomicAdd(&xout[curc*3+d], accx);
        accx = 0.f; curc = cc;
      }
      accx += cdS[i][d] * cwS[i];
    }
    atomicAdd(&xout[curc*3+d], accx);
  }
}

// ---- fused node MLP + next-layer projections (R6 version, 256 threads) ----
__global__ __launch_bounds__(256) void node2f_kernel(
    float* __restrict__ h, const float* __restrict__ magg,
    const short* __restrict__ W1ap, const short* __restrict__ W1bp,
    const float* __restrict__ bn1,
    const short* __restrict__ Wn2p, const float* __restrict__ bn2,
    const short* __restrict__ Wcp, const float* __restrict__ b1n,
    const short* __restrict__ Wrp,
    short* __restrict__ A, short* __restrict__ B, int doProj)
{
  __shared__ __align__(16) short hT[ME*HST];
  __shared__ __align__(16) short mT[ME*HST];
  __shared__ __align__(16) short bkS[2*4096];
  const int t = threadIdx.x;
  const int n0 = blockIdx.x * ME;
  {
    int nl = t >> 2, seg = t & 3;
    int n = n0 + nl; if (n >= NN) n = NN-1;
    const float4* hp = reinterpret_cast<const float4*>(h + (size_t)n*HID + seg*32);
    const float4* mp = reinterpret_cast<const float4*>(magg + (size_t)n*HID + seg*32);
    #pragma unroll
    for (int bq=0;bq<4;++bq){
      float4 u = hp[bq*2], v = hp[bq*2+1];
      int4 sv;
      sv.x = (int)cvtpk(u.x,u.y); sv.y = (int)cvtpk(u.z,u.w);
      sv.z = (int)cvtpk(v.x,v.y); sv.w = (int)cvtpk(v.z,v.w);
      *reinterpret_cast<int4*>(&hT[nl*HST + seg*32 + bq*8]) = sv;
      float4 u2 = mp[bq*2], v2 = mp[bq*2+1];
      int4 sv2;
      sv2.x = (int)cvtpk(u2.x,u2.y); sv2.y = (int)cvtpk(u2.z,u2.w);
      sv2.z = (int)cvtpk(v2.x,v2.y); sv2.w = (int)cvtpk(v2.z,v2.w);
      *reinterpret_cast<int4*>(&mT[nl*HST + seg*32 + bq*8]) = sv2;
    }
  }
  f32x4 z = {0.f,0.f,0.f,0.f};
  f32x4 acc[2][4];
  #pragma unroll
  for (int i=0;i<2;++i){ acc[i][0]=z; acc[i][1]=z; acc[i][2]=z; acc[i][3]=z; }
  gemm64(hT, HST, W1ap, 4, bkS, acc, t);
  gemm64(mT, HST, W1bp, 4, bkS, acc, t);        // accumulates
  epilogue_store(acc, bn1, nullptr, mT, t);      // silu1 -> mT
  __syncthreads();

  f32x4 acc2[2][4];
  #pragma unroll
  for (int i=0;i<2;++i){ acc2[i][0]=z; acc2[i][1]=z; acc2[i][2]=z; acc2[i][3]=z; }
  gemm64(mT, HST, Wn2p, 4, bkS, acc2, t);

  const int lane = t & 63, w = t >> 6;
  const int q = lane >> 4, fr = lane & 15;
  #pragma unroll
  for (int et=0; et<2; ++et){
    int e0 = (w&1)*32 + et*16 + q*4;
    #pragma unroll
    for (int ot=0; ot<4; ++ot){
      int o = (w>>1)*64 + ot*16 + fr;
      float bv = bn2[o];
      float hn[4];
      #pragma unroll
      for (int r=0;r<4;++r){
        int n = n0 + e0 + r;
        float hv = 0.f;
        if (n < NN){
          size_t idx = (size_t)n*HID + o;
          hv = h[idx] + acc2[et][ot][r] + bv;
          h[idx] = hv;
        }
        hn[r] = hv;
      }
      if (doProj){
        unsigned p01 = cvtpk(hn[0],hn[1]), p23 = cvtpk(hn[2],hn[3]);
        hT[(e0+0)*HST + o] = (short)p01;
        hT[(e0+1)*HST + o] = (short)(p01>>16);
        hT[(e0+2)*HST + o] = (short)p23;
        hT[(e0+3)*HST + o] = (short)(p23>>16);
      }
    }
  }
  if (!doProj) return;
  // (gemm64's loop-top barrier publishes hT)

  f32x4 accA[2][4], accB[2][4];
  #pragma unroll
  for (int i=0;i<2;++i){ accA[i][0]=z;accA[i][1]=z;accA[i][2]=z;accA[i][3]=z;
                         accB[i][0]=z;accB[i][1]=z;accB[i][2]=z;accB[i][3]=z; }
  gemm64(hT, HST, Wcp, 4, bkS, accA, t);
  gemm64(hT, HST, Wrp, 4, bkS, accB, t);
  #pragma unroll
  for (int et=0; et<2; ++et){
    int e0 = (w&1)*32 + et*16 + q*4;
    #pragma unroll
    for (int ot=0; ot<4; ++ot){
      int o = (w>>1)*64 + ot*16 + fr;
      float bv = b1n[o];
      #pragma unroll
      for (int r=0;r<4;++r){
        int n = n0 + e0 + r;
        if (n < NN){
          A[(size_t)n*HID + o] = bfr(accA[et][ot][r] + bv);
          B[(size_t)n*HID + o] = bfr(accB[et][ot][r]);
        }
      }
    }
  }
}

__global__ void pool_kernel(const float* __restrict__ h, const int* __restrict__ batch,
                            float* __restrict__ sums, float* __restrict__ counts){
  int o  = threadIdx.x;
  int n0 = blockIdx.x * 16;
  int curg = batch[n0];
  float accv = 0.f, cnt = 0.f;
  for (int j=0;j<16;++j){
    int n = n0 + j;
    int g = batch[n];
    if (g != curg){
      atomicAdd(&sums[(size_t)curg*HID+o], accv);
      if (o==0) atomicAdd(&counts[curg], cnt);
      accv = 0.f; cnt = 0.f; curg = g;
    }
    accv += h[(size_t)n*HID+o];
    cnt  += 1.f;
  }
  atomicAdd(&sums[(size_t)curg*HID+o], accv);
  if (o==0) atomicAdd(&counts[curg], cnt);
}

__global__ void out_kernel(const float* __restrict__ sums, const float* __restrict__ counts,
                           const float* __restrict__ rW, const float* __restrict__ rb,
                           float* __restrict__ out){
  int g = blockIdx.x; int t = threadIdx.x;
  float v = sums[(size_t)g*HID + t]*rW[t] + sums[(size_t)g*HID + 64 + t]*rW[64+t];
  #pragma unroll
  for (int off=32; off>0; off>>=1) v += __shfl_down(v, off);
  if (t==0) out[g] = v / fmaxf(counts[g], 1.0f) + rb[0];
}

extern "C" void kernel_launch(void* const* d_in, const int* in_sizes, int n_in,
                              void* d_out, int out_size, void* d_ws, size_t ws_size,
                              hipStream_t stream)
{
  const float* x_feat = (const float*)d_in[0];
  const float* pos    = (const float*)d_in[1];
  const float* eattr  = (const float*)d_in[2];
  const float* p      = (const float*)d_in[3];
  const float* embW   = (const float*)d_in[4];
  const float* embB   = (const float*)d_in[5];
  const float* eW1    = (const float*)d_in[6];
  const float* eb1    = (const float*)d_in[7];
  const float* eW2    = (const float*)d_in[8];
  const float* eb2    = (const float*)d_in[9];
  const float* gW     = (const float*)d_in[10];
  const float* gb     = (const float*)d_in[11];
  const float* nW1    = (const float*)d_in[12];
  const float* nb1    = (const float*)d_in[13];
  const float* nW2    = (const float*)d_in[14];
  const float* nb2    = (const float*)d_in[15];
  const float* cW1    = (const float*)d_in[16];
  const float* cb1    = (const float*)d_in[17];
  const float* cW2    = (const float*)d_in[18];
  const float* cb2    = (const float*)d_in[19];
  const float* rW     = (const float*)d_in[20];
  const float* rb     = (const float*)d_in[21];
  const int* eidx     = (const int*)d_in[22];
  const int* einv     = (const int*)d_in[23];
  const int* batch    = (const int*)d_in[24];

  float* ws = (float*)d_ws;
  float* h      = ws;  ws += (size_t)NN*HID;
  float* magg   = ws;  ws += (size_t)NN*HID;
  float* xA     = ws;  ws += NN*3;
  float* xB     = ws;  ws += NN*3;
  float* sums   = ws;  ws += (size_t)NG*HID;
  float* counts = ws;  ws += NG;
  int*   hist   = (int*)ws;  ws += NN;
  int*   se     = (int*)ws;  ws += NE;
  int2*  rcS    = (int2*)ws;  ws += (size_t)NE*2;
  float4* eaS   = (float4*)ws; ws += (size_t)NE*4;
  float* emS    = ws;  ws += NE;
  short* Abuf = (short*)ws;  ws += (size_t)NN*HID/2;
  short* Bbuf = (short*)ws;  ws += (size_t)NN*HID/2;
  const size_t PK = (size_t)NL*4*4*HID*8;   // shorts per packed array
  short* W1cp  = (short*)ws;
  short* W1rp  = W1cp  + PK;
  short* W2p   = W1rp  + PK;
  short* C1p   = W2p   + PK;
  short* Wn1ap = C1p   + PK;
  short* Wn1bp = Wn1ap + PK;
  short* Wn2p  = Wn1bp + PK;

  // counting sort of edges by col, then materialize sorted streams
  zero_hist<<<(NN+255)/256, 256, 0, stream>>>(hist);
  hist_kernel<<<(NE+255)/256, 256, 0, stream>>>(eidx, hist);
  scan_kernel<<<1, 1024, 0, stream>>>(hist, hist);
  scatter_kernel<<<(NE+255)/256, 256, 0, stream>>>(eidx, hist, se);
  reorder_kernel<<<(NE+255)/256, 256, 0, stream>>>(eidx, se, eattr, p, einv,
                                                   rcS, eaS, emS);

  // prepack bf16 weights (each [L][4][4][128][8])
  const int PG = (int)((PK + 255)/256);
  prepack_kernel<<<PG, 256, 0, stream>>>(eW1, W1cp, 261, 0);
  prepack_kernel<<<PG, 256, 0, stream>>>(eW1, W1rp, 261, 128);
  prepack_kernel<<<PG, 256, 0, stream>>>(eW2, W2p, 128, 0);
  prepack_kernel<<<PG, 256, 0, stream>>>(cW1, C1p, 128, 0);
  prepack_kernel<<<PG, 256, 0, stream>>>(nW1, Wn1ap, 256, 0);
  prepack_kernel<<<PG, 256, 0, stream>>>(nW1, Wn1bp, 256, 128);
  prepack_kernel<<<PG, 256, 0, stream>>>(nW2, Wn2p, 128, 0);

  hipMemcpyAsync(xA, pos, sizeof(float)*NN*3, hipMemcpyDeviceToDevice, stream);
  embed_kernel<<<NN, HID, 0, stream>>>(x_feat, embW, embB, h);
  nodeproj_kernel<<<NPB, 256, 0, stream>>>(h, W1cp, eb1, W1rp, Abuf, Bbuf);

  float* xc = xA; float* xn = xB;
  for (int l=0;l<NL;++l){
    const size_t wofs = (size_t)l*4*4096;
    const size_t wofsn = (size_t)(l+1)*4*4096;
    hipMemsetAsync(magg, 0, sizeof(float)*(size_t)NN*HID, stream);
    hipMemcpyAsync(xn, xc, sizeof(float)*NN*3, hipMemcpyDeviceToDevice, stream);
    edge2_kernel<<<NWGE, 512, 0, stream>>>(Abuf, Bbuf, xc, rcS, eaS, emS,
        eW1 + (size_t)l*261*HID,
        W2p + wofs, eb2 + l*HID,
        gW  + l*HID, gb + l,
        C1p + wofs, cb1 + l*HID,
        cW2 + l*HID, cb2 + l,
        magg, xn);
    int doProj = (l+1 < NL);
    node2f_kernel<<<NPB, 256, 0, stream>>>(h, magg,
        Wn1ap + wofs, Wn1bp + wofs, nb1 + l*HID,
        Wn2p + wofs, nb2 + l*HID,
        W1cp + (doProj?wofsn:0), eb1 + (doProj?(l+1)*HID:0),
        W1rp + (doProj?wofsn:0),
        Abuf, Bbuf, doProj);
    float* tmp = xc; xc = xn; xn = tmp;
  }
  hipMemsetAsync(sums, 0, sizeof(float)*((size_t)NG*HID + NG), stream);
  pool_kernel<<<NN/16, HID, 0, stream>>>(h, batch, sums, counts);
  out_kernel<<<NG, 64, 0, stream>>>(sums, counts, rW, rb, (float*)d_out);
}

// Round 11
// 1562.311 us; speedup vs baseline: 1.2208x; 1.0722x over previous
//
#include <hip/hip_runtime.h>

#define NN 50000
#define NE 800000
#define HID 128
#define NG 2500
#define NL 4
#define ME 64       // edges (or nodes) per block
#define HST 136     // LDS tile row stride (shorts): 272B, bank-phase 4 -> 2-way max (free)
#define NPB 782     // node blocks: ceil(50000/64)
#define NWG (NE/ME) // 12500 edge blocks

typedef __attribute__((ext_vector_type(8))) short short8v;
typedef __attribute__((ext_vector_type(4))) float f32x4;

__device__ __forceinline__ float sigf(float x){ return 1.0f/(1.0f+__expf(-x)); }
__device__ __forceinline__ float siluf(float x){ return x/(1.0f+__expf(-x)); }
__device__ __forceinline__ short bfr(float x){           // scalar f32->bf16 (RNE)
  unsigned u = __float_as_uint(x);
  u += 0x7fffu + ((u>>16)&1u);
  return (short)(u>>16);
}
__device__ __forceinline__ unsigned cvtpk(float lo, float hi){
  unsigned r;
  asm("v_cvt_pk_bf16_f32 %0, %1, %2" : "=v"(r) : "v"(lo), "v"(hi));
  return r;
}
__device__ __forceinline__ float bf2f(short s){
  return __uint_as_float(((unsigned)(unsigned short)s)<<16);
}

// ---------------- counting sort of edges by col (hist zeroed via memset) ----------------
__global__ void hist_kernel(const int* __restrict__ eidx, int* __restrict__ hist){
  int e = blockIdx.x*256 + threadIdx.x;
  if (e < NE) atomicAdd(&hist[eidx[NE+e]], 1);
}
__global__ __launch_bounds__(1024) void scan_kernel(const int* __restrict__ hist,
                                                    int* __restrict__ cursor){
  __shared__ int part[1024];
  int t = threadIdx.x;
  const int CH = (NN + 1023)/1024;
  int base = t*CH;
  int s = 0;
  for (int j=0;j<CH;++j){ int i=base+j; if (i<NN) s += hist[i]; }
  part[t] = s; __syncthreads();
  for (int d=1; d<1024; d<<=1){
    int v = (t>=d) ? part[t-d] : 0;
    __syncthreads();
    part[t] += v;
    __syncthreads();
  }
  int ex = (t==0) ? 0 : part[t-1];
  for (int j=0;j<CH;++j){
    int i=base+j;
    if (i<NN){ cursor[i] = ex; ex += hist[i]; }
  }
}
// fused scatter + stream materialization: one pass, no se[] indirection
__global__ void scatter_kernel(const int* __restrict__ eidx, int* __restrict__ cursor,
                               const float* __restrict__ ea, const float* __restrict__ p,
                               const int* __restrict__ inv,
                               int2* __restrict__ rcS, float4* __restrict__ eaS,
                               float* __restrict__ emS){
  int e = blockIdx.x*256 + threadIdx.x;
  if (e < NE){
    int r = eidx[e], c = eidx[NE+e];
    int pos = atomicAdd(&cursor[c], 1);
    int2 rc; rc.x = r; rc.y = c;
    rcS[pos] = rc;
    eaS[pos] = *reinterpret_cast<const float4*>(ea + (size_t)e*4);
    emS[pos] = (p[inv[e]] >= 0.0f) ? 1.0f : 0.0f;
  }
}

// ---- weight prepack: rows [roff,roff+128) of [L][Ktot][128] -> [L][ks4][q4][o128][kk8] bf16
__global__ void prepack_kernel(const float* __restrict__ W, short* __restrict__ out,
                               int Ktot, int roff){
  int idx = blockIdx.x*256 + threadIdx.x;
  if (idx >= NL*4*4*HID*8) return;
  int kk8 = idx & 7;
  int o   = (idx>>3) & 127;
  int q   = (idx>>10) & 3;
  int ks  = (idx>>12) & 3;
  int l   = idx >> 14;
  int k = roff + ks*32 + q*8 + kk8;
  float v = (k < Ktot) ? W[((size_t)l*Ktot + k)*HID + o] : 0.0f;
  out[idx] = bfr(v);
}

__global__ void embed_kernel(const float* __restrict__ xf, const float* __restrict__ W,
                             const float* __restrict__ b, float* __restrict__ h){
  int n = blockIdx.x; int o = threadIdx.x;
  float s = b[o];
  #pragma unroll
  for (int i=0;i<11;++i) s = fmaf(xf[n*11+i], W[i*HID+o], s);
  h[(size_t)n*HID+o] = s;
}

// ---------------- MFMA tile-GEMM: [64 x 128] (LDS bf16) @ [128 x 128] (prepacked) ----
__device__ __forceinline__ void gemm64(const short* As, int astride,
                                       const short* Wp, int nks,
                                       short* bkS, f32x4 acc[2][4], int t)
{
  const int lane = t & 63, w = t >> 6;
  const int q = lane >> 4, fr = lane & 15;
  const int erow = (w & 1) * 32;
  const int ocol = (w >> 1) * 64;
  const int4* g = reinterpret_cast<const int4*>(Wp);
  int4* bkw = reinterpret_cast<int4*>(bkS);
  int4 p0 = g[t], p1 = g[256 + t];
  for (int ks = 0; ks < nks; ++ks){
    const int buf = (ks & 1) * 512;            // int4 units (4096 shorts)
    bkw[buf + t] = p0; bkw[buf + 256 + t] = p1;
    __syncthreads();
    if (ks + 1 < nks){ p0 = g[(ks+1)*512 + t]; p1 = g[(ks+1)*512 + 256 + t]; }
    const short* bb = bkS + buf*8 + q*1024;
    short8v a[2], b[4];
    #pragma unroll
    for (int et=0; et<2; ++et)
      a[et] = *reinterpret_cast<const short8v*>(As + (erow + et*16 + fr)*astride + ks*32 + q*8);
    #pragma unroll
    for (int ot=0; ot<4; ++ot)
      b[ot] = *reinterpret_cast<const short8v*>(bb + (ocol + ot*16 + fr)*8);
    #pragma unroll
    for (int et=0; et<2; ++et)
      #pragma unroll
      for (int ot=0; ot<4; ++ot)
        acc[et][ot] = __builtin_amdgcn_mfma_f32_16x16x32_bf16(a[et], b[ot], acc[et][ot], 0, 0, 0);
  }
  __syncthreads();
}

// acc -> silu(scale*acc + bias) -> bf16 LDS tile [64][HST]; scaleS==nullptr -> scale=1
__device__ __forceinline__ void epilogue_store(const f32x4 acc[2][4],
                                               const float* __restrict__ bias,
                                               const float* __restrict__ scaleS,
                                               short* dst, int t)
{
  const int lane = t & 63, w = t >> 6;
  const int q = lane >> 4, fr = lane & 15;
  #pragma unroll
  for (int et=0; et<2; ++et){
    const int e0 = (w&1)*32 + et*16 + q*4;
    float s0=1.f,s1=1.f,s2=1.f,s3=1.f;
    if (scaleS){ s0=scaleS[e0]; s1=scaleS[e0+1]; s2=scaleS[e0+2]; s3=scaleS[e0+3]; }
    #pragma unroll
    for (int ot=0; ot<4; ++ot){
      int o = (w>>1)*64 + ot*16 + fr;
      float bv = bias[o];
      unsigned p01 = cvtpk(siluf(fmaf(s0,acc[et][ot][0],bv)), siluf(fmaf(s1,acc[et][ot][1],bv)));
      unsigned p23 = cvtpk(siluf(fmaf(s2,acc[et][ot][2],bv)), siluf(fmaf(s3,acc[et][ot][3],bv)));
      dst[(e0+0)*HST + o] = (short)p01;
      dst[(e0+1)*HST + o] = (short)(p01>>16);
      dst[(e0+2)*HST + o] = (short)p23;
      dst[(e0+3)*HST + o] = (short)(p23>>16);
    }
  }
}

// ---------------- layer-0 node projections: A = bf16(h@W1hc + b1), B = bf16(h@W1hr) ----
__global__ __launch_bounds__(256) void nodeproj_kernel(
    const float* __restrict__ h,
    const short* __restrict__ Wcp, const float* __restrict__ b1,
    const short* __restrict__ Wrp,
    short* __restrict__ A, short* __restrict__ B)
{
  __shared__ __align__(16) short hT[ME*HST];
  __shared__ __align__(16) short bkS[2*4096];
  const int t = threadIdx.x;
  const int n0 = blockIdx.x * ME;
  {
    int nl = t >> 2, seg = t & 3;
    int n = n0 + nl; if (n >= NN) n = NN-1;
    const float4* hp = reinterpret_cast<const float4*>(h + (size_t)n*HID + seg*32);
    #pragma unroll
    for (int bq=0;bq<4;++bq){
      float4 u = hp[bq*2], v = hp[bq*2+1];
      int4 sv;
      sv.x = (int)cvtpk(u.x,u.y); sv.y = (int)cvtpk(u.z,u.w);
      sv.z = (int)cvtpk(v.x,v.y); sv.w = (int)cvtpk(v.z,v.w);
      *reinterpret_cast<int4*>(&hT[nl*HST + seg*32 + bq*8]) = sv;
    }
  }
  f32x4 z = {0.f,0.f,0.f,0.f};
  f32x4 accA[2][4], accB[2][4];
  #pragma unroll
  for (int i=0;i<2;++i){ accA[i][0]=z;accA[i][1]=z;accA[i][2]=z;accA[i][3]=z;
                         accB[i][0]=z;accB[i][1]=z;accB[i][2]=z;accB[i][3]=z; }
  gemm64(hT, HST, Wcp, 4, bkS, accA, t);
  gemm64(hT, HST, Wrp, 4, bkS, accB, t);
  const int lane = t & 63, w = t >> 6;
  const int q = lane >> 4, fr = lane & 15;
  #pragma unroll
  for (int et=0; et<2; ++et){
    int e0 = (w&1)*32 + et*16 + q*4;
    #pragma unroll
    for (int ot=0; ot<4; ++ot){
      int o = (w>>1)*64 + ot*16 + fr;
      float bv = b1[o];
      #pragma unroll
      for (int r=0;r<4;++r){
        int n = n0 + e0 + r;
        if (n < NN){
          A[(size_t)n*HID + o] = bfr(accA[et][ot][r] + bv);
          B[(size_t)n*HID + o] = bfr(accB[et][ot][r]);
        }
      }
    }
  }
}

// ---------------- edge kernel (R6 structure) ----------------
__global__ __launch_bounds__(256) void edge2_kernel(
    const short* __restrict__ A, const short* __restrict__ B,
    const float* __restrict__ x,
    const int2* __restrict__ rcS, const float4* __restrict__ eaS,
    const float* __restrict__ emS,
    const float* __restrict__ wrow,   // eW1 + l*261*128 : rows 256..260 = wd, wea
    const short* __restrict__ W2p, const float* __restrict__ b2,
    const float* __restrict__ Wg, const float* __restrict__ bg,
    const short* __restrict__ C1p, const float* __restrict__ bc1,
    const float* __restrict__ Wc2, const float* __restrict__ cb2,
    float* __restrict__ magg, float* __restrict__ xout)
{
  __shared__ __align__(16) short hidS[ME*HST];   // hidden1 -> m_pre (kept) -> hidden2
  __shared__ __align__(16) short bkS[2*4096];
  __shared__ float wdS[HID], wgS[HID], wc2S[HID];
  __shared__ float weaS[4][HID];
  __shared__ float maskS[ME], scaleS[ME], cwS[ME], distS[ME], cdS[ME][3];
  __shared__ int colS[ME];

  const int t = threadIdx.x;
  // bijective XCD swizzle (m204)
  const int xcd = blockIdx.x & 7, sub = blockIdx.x >> 3;
  const int qq = NWG >> 3, rr = NWG & 7;
  const int bid = (xcd < rr ? xcd*(qq+1) : rr*(qq+1) + (xcd-rr)*qq) + sub;
  const int i0 = bid * ME;

  // issue per-thread gathers early (4 threads/edge, 32 channels each)
  const int el = t >> 2, seg = t & 3;
  const int2 rc = rcS[i0 + el];
  const int4* Ap = reinterpret_cast<const int4*>(A + (size_t)rc.y*HID + seg*32);
  const int4* Bp = reinterpret_cast<const int4*>(B + (size_t)rc.x*HID + seg*32);
  int4 av0=Ap[0], av1=Ap[1], av2=Ap[2], av3=Ap[3];
  int4 bv0=Bp[0], bv1=Bp[1], bv2=Bp[2], bv3=Bp[3];
  float4 eav = eaS[i0 + el];

  if (t < HID){
    wdS[t] = wrow[256*HID + t];
    wgS[t] = Wg[t]; wc2S[t] = Wc2[t];
    #pragma unroll
    for (int j=0;j<4;++j) weaS[j][t] = wrow[(257+j)*HID + t];
  }
  if (t < ME){
    int2 rc2 = rcS[i0 + t];
    colS[t] = rc2.y; maskS[t] = emS[i0 + t];
    float dx = x[rc2.y*3+0]-x[rc2.x*3+0];
    float dy = x[rc2.y*3+1]-x[rc2.x*3+1];
    float dz = x[rc2.y*3+2]-x[rc2.x*3+2];
    cdS[t][0]=dx; cdS[t][1]=dy; cdS[t][2]=dz;
    distS[t] = sqrtf(dx*dx+dy*dy+dz*dz);
  }
  __syncthreads();

  // hidden1 = silu(A[col] + B[row] + dist*wd + ea@wea)
  {
    float de = distS[el];
    const int4 avs[4] = {av0,av1,av2,av3};
    const int4 bvs[4] = {bv0,bv1,bv2,bv3};
    #pragma unroll
    for (int bq=0;bq<4;++bq){
      short8v a8 = *reinterpret_cast<const short8v*>(&avs[bq]);
      short8v b8 = *reinterpret_cast<const short8v*>(&bvs[bq]);
      float f[8];
      #pragma unroll
      for (int j=0;j<8;++j){
        int o = seg*32 + bq*8 + j;
        float v = bf2f(a8[j]) + bf2f(b8[j]) + de*wdS[o]
                + eav.x*weaS[0][o] + eav.y*weaS[1][o]
                + eav.z*weaS[2][o] + eav.w*weaS[3][o];
        f[j] = siluf(v);
      }
      int4 sv;
      sv.x = (int)cvtpk(f[0],f[1]); sv.y = (int)cvtpk(f[2],f[3]);
      sv.z = (int)cvtpk(f[4],f[5]); sv.w = (int)cvtpk(f[6],f[7]);
      *reinterpret_cast<int4*>(&hidS[el*HST + seg*32 + bq*8]) = sv;
    }
  }
  // gemm64's first loop-top barrier publishes hidS

  f32x4 z = {0.f,0.f,0.f,0.f};
  f32x4 acc2[2][4];
  #pragma unroll
  for (int i=0;i<2;++i){ acc2[i][0]=z; acc2[i][1]=z; acc2[i][2]=z; acc2[i][3]=z; }
  gemm64(hidS, HST, W2p, 4, bkS, acc2, t);
  epilogue_store(acc2, b2, nullptr, hidS, t);     // m_pre (in-place)
  __syncthreads();                                // publish m_pre

  // gate = sigmoid(m_pre . Wg + bg) * mask   (4 threads per edge)
  {
    int eg = t >> 2, g = t & 3;
    float p = 0.f;
    #pragma unroll
    for (int bq=0;bq<4;++bq){
      short8v s = *reinterpret_cast<const short8v*>(&hidS[eg*HST + g*32 + bq*8]);
      #pragma unroll
      for (int j=0;j<8;++j) p += bf2f(s[j]) * wgS[g*32 + bq*8 + j];
    }
    p += __shfl_xor(p, 1); p += __shfl_xor(p, 2);
    if (g == 0) scaleS[eg] = sigf(p + bg[0]) * maskS[eg];
  }
  __syncthreads();                                // publish scaleS

  // magg[col] += m_pre * scale (segmented; m_pre NOT modified — scale folded into C1)
  // no trailing barrier needed: gemm3 only writes bkS (protected by gemm2's trailing
  // barrier) and its loop-top barrier orders everything else.
  {
    int o = t & 127, half = t >> 7;
    int ib = half*32;
    float accv = 0.f;
    int curc = colS[ib];
    #pragma unroll 4
    for (int j=0;j<32;++j){
      int i = ib + j;
      int cc = colS[i];
      if (cc != curc){
        atomicAdd(&magg[(size_t)curc*HID + o], accv);
        accv = 0.f; curc = cc;
      }
      accv += bf2f(hidS[i*HST + o]) * scaleS[i];
    }
    atomicAdd(&magg[(size_t)curc*HID + o], accv);
  }

  // hidden2 = silu(scale * (m_pre @ Wc1) + bc1)
  f32x4 acc3[2][4];
  #pragma unroll
  for (int i=0;i<2;++i){ acc3[i][0]=z; acc3[i][1]=z; acc3[i][2]=z; acc3[i][3]=z; }
  gemm64(hidS, HST, C1p, 4, bkS, acc3, t);
  epilogue_store(acc3, bc1, scaleS, hidS, t);     // hidden2 (in-place)
  __syncthreads();                                // publish hidden2

  // cw = hidden2 . Wc2 + cb2
  {
    int eg = t >> 2, g = t & 3;
    float p = 0.f;
    #pragma unroll
    for (int bq=0;bq<4;++bq){
      short8v s = *reinterpret_cast<const short8v*>(&hidS[eg*HST + g*32 + bq*8]);
      #pragma unroll
      for (int j=0;j<8;++j) p += bf2f(s[j]) * wc2S[g*32 + bq*8 + j];
    }
    p += __shfl_xor(p, 1); p += __shfl_xor(p, 2);
    if (g == 0) cwS[eg] = p + cb2[0];
  }
  __syncthreads();                                // publish cwS

  // x_out[col] += coord_diff * cw (segmented)
  if (t < 6){
    int d = t % 3, half = t / 3;
    int ib = half*32;
    float accx = 0.f;
    int curc = colS[ib];
    for (int j=0;j<32;++j){
      int i = ib + j;
      int cc = colS[i];
      if (cc != curc){
        atomicAdd(&xout[curc*3+d], accx);
        accx = 0.f; curc = cc;
      }
      accx += cdS[i][d] * cwS[i];
    }
    atomicAdd(&xout[curc*3+d], accx);
  }
}

// ---- fused node MLP + next-layer projections (R6 version) ----
__global__ __launch_bounds__(256) void node2f_kernel(
    float* __restrict__ h, const float* __restrict__ magg,
    const short* __restrict__ W1ap, const short* __restrict__ W1bp,
    const float* __restrict__ bn1,
    const short* __restrict__ Wn2p, const float* __restrict__ bn2,
    const short* __restrict__ Wcp, const float* __restrict__ b1n,
    const short* __restrict__ Wrp,
    short* __restrict__ A, short* __restrict__ B, int doProj)
{
  __shared__ __align__(16) short hT[ME*HST];
  __shared__ __align__(16) short mT[ME*HST];
  __shared__ __align__(16) short bkS[2*4096];
  const int t = threadIdx.x;
  const int n0 = blockIdx.x * ME;
  {
    int nl = t >> 2, seg = t & 3;
    int n = n0 + nl; if (n >= NN) n = NN-1;
    const float4* hp = reinterpret_cast<const float4*>(h + (size_t)n*HID + seg*32);
    const float4* mp = reinterpret_cast<const float4*>(magg + (size_t)n*HID + seg*32);
    #pragma unroll
    for (int bq=0;bq<4;++bq){
      float4 u = hp[bq*2], v = hp[bq*2+1];
      int4 sv;
      sv.x = (int)cvtpk(u.x,u.y); sv.y = (int)cvtpk(u.z,u.w);
      sv.z = (int)cvtpk(v.x,v.y); sv.w = (int)cvtpk(v.z,v.w);
      *reinterpret_cast<int4*>(&hT[nl*HST + seg*32 + bq*8]) = sv;
      float4 u2 = mp[bq*2], v2 = mp[bq*2+1];
      int4 sv2;
      sv2.x = (int)cvtpk(u2.x,u2.y); sv2.y = (int)cvtpk(u2.z,u2.w);
      sv2.z = (int)cvtpk(v2.x,v2.y); sv2.w = (int)cvtpk(v2.z,v2.w);
      *reinterpret_cast<int4*>(&mT[nl*HST + seg*32 + bq*8]) = sv2;
    }
  }
  f32x4 z = {0.f,0.f,0.f,0.f};
  f32x4 acc[2][4];
  #pragma unroll
  for (int i=0;i<2;++i){ acc[i][0]=z; acc[i][1]=z; acc[i][2]=z; acc[i][3]=z; }
  gemm64(hT, HST, W1ap, 4, bkS, acc, t);
  gemm64(mT, HST, W1bp, 4, bkS, acc, t);        // accumulates
  epilogue_store(acc, bn1, nullptr, mT, t);      // silu1 -> mT
  __syncthreads();

  f32x4 acc2[2][4];
  #pragma unroll
  for (int i=0;i<2;++i){ acc2[i][0]=z; acc2[i][1]=z; acc2[i][2]=z; acc2[i][3]=z; }
  gemm64(mT, HST, Wn2p, 4, bkS, acc2, t);

  const int lane = t & 63, w = t >> 6;
  const int q = lane >> 4, fr = lane & 15;
  #pragma unroll
  for (int et=0; et<2; ++et){
    int e0 = (w&1)*32 + et*16 + q*4;
    #pragma unroll
    for (int ot=0; ot<4; ++ot){
      int o = (w>>1)*64 + ot*16 + fr;
      float bv = bn2[o];
      float hn[4];
      #pragma unroll
      for (int r=0;r<4;++r){
        int n = n0 + e0 + r;
        float hv = 0.f;
        if (n < NN){
          size_t idx = (size_t)n*HID + o;
          hv = h[idx] + acc2[et][ot][r] + bv;
          h[idx] = hv;
        }
        hn[r] = hv;
      }
      if (doProj){
        unsigned p01 = cvtpk(hn[0],hn[1]), p23 = cvtpk(hn[2],hn[3]);
        hT[(e0+0)*HST + o] = (short)p01;
        hT[(e0+1)*HST + o] = (short)(p01>>16);
        hT[(e0+2)*HST + o] = (short)p23;
        hT[(e0+3)*HST + o] = (short)(p23>>16);
      }
    }
  }
  if (!doProj) return;
  // (gemm64's loop-top barrier publishes hT)

  f32x4 accA[2][4], accB[2][4];
  #pragma unroll
  for (int i=0;i<2;++i){ accA[i][0]=z;accA[i][1]=z;accA[i][2]=z;accA[i][3]=z;
                         accB[i][0]=z;accB[i][1]=z;accB[i][2]=z;accB[i][3]=z; }
  gemm64(hT, HST, Wcp, 4, bkS, accA, t);
  gemm64(hT, HST, Wrp, 4, bkS, accB, t);
  #pragma unroll
  for (int et=0; et<2; ++et){
    int e0 = (w&1)*32 + et*16 + q*4;
    #pragma unroll
    for (int ot=0; ot<4; ++ot){
      int o = (w>>1)*64 + ot*16 + fr;
      float bv = b1n[o];
      #pragma unroll
      for (int r=0;r<4;++r){
        int n = n0 + e0 + r;
        if (n < NN){
          A[(size_t)n*HID + o] = bfr(accA[et][ot][r] + bv);
          B[(size_t)n*HID + o] = bfr(accB[et][ot][r]);
        }
      }
    }
  }
}

__global__ void pool_kernel(const float* __restrict__ h, const int* __restrict__ batch,
                            float* __restrict__ sums, float* __restrict__ counts){
  int o  = threadIdx.x;
  int n0 = blockIdx.x * 16;
  int curg = batch[n0];
  float accv = 0.f, cnt = 0.f;
  for (int j=0;j<16;++j){
    int n = n0 + j;
    int g = batch[n];
    if (g != curg){
      atomicAdd(&sums[(size_t)curg*HID+o], accv);
      if (o==0) atomicAdd(&counts[curg], cnt);
      accv = 0.f; cnt = 0.f; curg = g;
    }
    accv += h[(size_t)n*HID+o];
    cnt  += 1.f;
  }
  atomicAdd(&sums[(size_t)curg*HID+o], accv);
  if (o==0) atomicAdd(&counts[curg], cnt);
}

__global__ void out_kernel(const float* __restrict__ sums, const float* __restrict__ counts,
                           const float* __restrict__ rW, const float* __restrict__ rb,
                           float* __restrict__ out){
  int g = blockIdx.x; int t = threadIdx.x;
  float v = sums[(size_t)g*HID + t]*rW[t] + sums[(size_t)g*HID + 64 + t]*rW[64+t];
  #pragma unroll
  for (int off=32; off>0; off>>=1) v += __shfl_down(v, off);
  if (t==0) out[g] = v / fmaxf(counts[g], 1.0f) + rb[0];
}

extern "C" void kernel_launch(void* const* d_in, const int* in_sizes, int n_in,
                              void* d_out, int out_size, void* d_ws, size_t ws_size,
                              hipStream_t stream)
{
  const float* x_feat = (const float*)d_in[0];
  const float* pos    = (const float*)d_in[1];
  const float* eattr  = (const float*)d_in[2];
  const float* p      = (const float*)d_in[3];
  const float* embW   = (const float*)d_in[4];
  const float* embB   = (const float*)d_in[5];
  const float* eW1    = (const float*)d_in[6];
  const float* eb1    = (const float*)d_in[7];
  const float* eW2    = (const float*)d_in[8];
  const float* eb2    = (const float*)d_in[9];
  const float* gW     = (const float*)d_in[10];
  const float* gb     = (const float*)d_in[11];
  const float* nW1    = (const float*)d_in[12];
  const float* nb1    = (const float*)d_in[13];
  const float* nW2    = (const float*)d_in[14];
  const float* nb2    = (const float*)d_in[15];
  const float* cW1    = (const float*)d_in[16];
  const float* cb1    = (const float*)d_in[17];
  const float* cW2    = (const float*)d_in[18];
  const float* cb2    = (const float*)d_in[19];
  const float* rW     = (const float*)d_in[20];
  const float* rb     = (const float*)d_in[21];
  const int* eidx     = (const int*)d_in[22];
  const int* einv     = (const int*)d_in[23];
  const int* batch    = (const int*)d_in[24];

  float* ws = (float*)d_ws;
  float* h      = ws;  ws += (size_t)NN*HID;
  float* magg   = ws;  ws += (size_t)NN*HID;
  float* xA     = ws;  ws += NN*3;
  float* xB     = ws;  ws += NN*3;
  float* sums   = ws;  ws += (size_t)NG*HID;
  float* counts = ws;  ws += NG;
  int*   hist   = (int*)ws;  ws += NN;
  int2*  rcS    = (int2*)ws;  ws += (size_t)NE*2;
  float4* eaS   = (float4*)ws; ws += (size_t)NE*4;
  float* emS    = ws;  ws += NE;
  short* Abuf = (short*)ws;  ws += (size_t)NN*HID/2;
  short* Bbuf = (short*)ws;  ws += (size_t)NN*HID/2;
  const size_t PK = (size_t)NL*4*4*HID*8;   // shorts per packed array
  short* W1cp  = (short*)ws;
  short* W1rp  = W1cp  + PK;
  short* W2p   = W1rp  + PK;
  short* C1p   = W2p   + PK;
  short* Wn1ap = C1p   + PK;
  short* Wn1bp = Wn1ap + PK;
  short* Wn2p  = Wn1bp + PK;

  // counting sort of edges by col; scatter materializes sorted streams directly
  hipMemsetAsync(hist, 0, sizeof(int)*NN, stream);
  hist_kernel<<<(NE+255)/256, 256, 0, stream>>>(eidx, hist);
  scan_kernel<<<1, 1024, 0, stream>>>(hist, hist);
  scatter_kernel<<<(NE+255)/256, 256, 0, stream>>>(eidx, hist, eattr, p, einv,
                                                   rcS, eaS, emS);

  // prepack bf16 weights (each [L][4][4][128][8])
  const int PG = (int)((PK + 255)/256);
  prepack_kernel<<<PG, 256, 0, stream>>>(eW1, W1cp, 261, 0);
  prepack_kernel<<<PG, 256, 0, stream>>>(eW1, W1rp, 261, 128);
  prepack_kernel<<<PG, 256, 0, stream>>>(eW2, W2p, 128, 0);
  prepack_kernel<<<PG, 256, 0, stream>>>(cW1, C1p, 128, 0);
  prepack_kernel<<<PG, 256, 0, stream>>>(nW1, Wn1ap, 256, 0);
  prepack_kernel<<<PG, 256, 0, stream>>>(nW1, Wn1bp, 256, 128);
  prepack_kernel<<<PG, 256, 0, stream>>>(nW2, Wn2p, 128, 0);

  hipMemcpyAsync(xA, pos, sizeof(float)*NN*3, hipMemcpyDeviceToDevice, stream);
  embed_kernel<<<NN, HID, 0, stream>>>(x_feat, embW, embB, h);
  // layer-0 projections
  nodeproj_kernel<<<NPB, 256, 0, stream>>>(h, W1cp, eb1, W1rp, Abuf, Bbuf);

  float* xc = xA; float* xn = xB;
  for (int l=0;l<NL;++l){
    const size_t wofs = (size_t)l*4*4096;
    const size_t wofsn = (size_t)(l+1)*4*4096;
    hipMemsetAsync(magg, 0, sizeof(float)*(size_t)NN*HID, stream);
    hipMemcpyAsync(xn, xc, sizeof(float)*NN*3, hipMemcpyDeviceToDevice, stream);
    edge2_kernel<<<NWG, 256, 0, stream>>>(Abuf, Bbuf, xc, rcS, eaS, emS,
        eW1 + (size_t)l*261*HID,
        W2p + wofs, eb2 + l*HID,
        gW  + l*HID, gb + l,
        C1p + wofs, cb1 + l*HID,
        cW2 + l*HID, cb2 + l,
        magg, xn);
    int doProj = (l+1 < NL);
    node2f_kernel<<<NPB, 256, 0, stream>>>(h, magg,
        Wn1ap + wofs, Wn1bp + wofs, nb1 + l*HID,
        Wn2p + wofs, nb2 + l*HID,
        W1cp + (doProj?wofsn:0), eb1 + (doProj?(l+1)*HID:0),
        W1rp + (doProj?wofsn:0),
        Abuf, Bbuf, doProj);
    float* tmp = xc; xc = xn; xn = tmp;
  }
  hipMemsetAsync(sums, 0, sizeof(float)*((size_t)NG*HID + NG), stream);
  pool_kernel<<<NN/16, HID, 0, stream>>>(h, batch, sums, counts);
  out_kernel<<<NG, 64, 0, stream>>>(sums, counts, rW, rb, (float*)d_out);
}